// Round 1
// baseline (203.570 us; speedup 1.0000x reference)
//
#include <hip/hip_runtime.h>
#include <hip/hip_bf16.h>

#define NSP 4096   // H*W
#define CCH 256    // C
#define CIN 128    // Ci
#define BN_EPS 1e-5f

typedef __bf16 bf16x8 __attribute__((ext_vector_type(8)));
typedef __bf16 bf16x4 __attribute__((ext_vector_type(4)));
typedef float f32x4 __attribute__((ext_vector_type(4)));
typedef unsigned short u16x8 __attribute__((ext_vector_type(8)));

// ================= fp32 tile helpers (prep only) =================================

__device__ __forceinline__ float4 fetch_tr(const float* __restrict__ A, int lda, int m0,
                                           int k0, int tid) {
  const int r = tid >> 2, kq = (tid & 3) << 2;
  return *(const float4*)(A + (size_t)(m0 + r) * lda + k0 + kq);
}
__device__ __forceinline__ void stash_tr(float (*As)[68], float4 v, int tid) {
  const int r = tid >> 2, kq = (tid & 3) << 2;
  As[kq + 0][r] = v.x; As[kq + 1][r] = v.y; As[kq + 2][r] = v.z; As[kq + 3][r] = v.w;
}
__device__ __forceinline__ float4 fetch_dir(const float* __restrict__ B, int ldb, int k0,
                                            int n0, int tid) {
  const int kr = tid >> 4, nq = (tid & 15) << 2;
  return *(const float4*)(B + (size_t)(k0 + kr) * ldb + n0 + nq);
}
__device__ __forceinline__ void stash_dir(float (*Bs)[68], float4 v, int tid) {
  const int kr = tid >> 4, nq = (tid & 15) << 2;
  *(float4*)(&Bs[kr][nq]) = v;
}

__device__ __forceinline__ void mm16(const float (*As)[68], const float (*Bs)[68],
                                     float acc[4][4], int ty, int tx) {
#pragma unroll
  for (int kk = 0; kk < 16; ++kk) {
    const float4 av = *(const float4*)(&As[kk][ty << 2]);
    const float4 bv = *(const float4*)(&Bs[kk][tx << 2]);
    const float ar[4] = {av.x, av.y, av.z, av.w};
    const float br[4] = {bv.x, bv.y, bv.z, bv.w};
#pragma unroll
    for (int i = 0; i < 4; ++i)
#pragma unroll
      for (int j = 0; j < 4; ++j) acc[i][j] += ar[i] * br[j];
  }
}

__device__ __forceinline__ float wave_reduce(float v) {
#pragma unroll
  for (int off = 32; off; off >>= 1) v += __shfl_down(v, off);
  return v;  // valid in lane 0
}

// ===== k0: all independent prep in one dispatch =================================
// cast_b+srow(0..1023) + cast_a(1024..2047) + prep(2048..2079) + vb/d1(2080)
// + vpt(2081) + wgb(2082..2085)
__global__ __launch_bounds__(256) void prep_kernel(
    const float* __restrict__ bin, const float* __restrict__ a,
    const float* __restrict__ W_w, const float* __restrict__ g_w,
    const float* __restrict__ phi_w, const float* __restrict__ theta_w,
    const float* __restrict__ phi_b, const float* __restrict__ theta_b,
    const float* __restrict__ g_b,
    __bf16* __restrict__ bhi, __bf16* __restrict__ blo,
    float* __restrict__ srow,
    float* __restrict__ Wg, __bf16* __restrict__ Wghi, __bf16* __restrict__ Wglo,
    __bf16* __restrict__ PTthi, __bf16* __restrict__ PTtlo,
    __bf16* __restrict__ at,
    float* __restrict__ vb_g, float* __restrict__ vpt, float* __restrict__ wgb,
    float* __restrict__ dvec) {
  __shared__ float smem[64 * 68];
  const int idx = blockIdx.x;
  const int t = threadIdx.x;
  const int wave = t >> 6, lane = t & 63;
  if (idx < 1024) {
    // ---- cast b -> bf16 hi/lo (truncation, identical to old f8_hilo) + exact srow
    const int row = idx;  // global row over 4*256
    const float* src = bin + (size_t)row * NSP + t * 16;
    float sum = 0.f;
    unsigned short h16[16], l16[16];
#pragma unroll
    for (int i = 0; i < 4; ++i) {
      const float4 v = *(const float4*)(src + i * 4);
      const float vv[4] = {v.x, v.y, v.z, v.w};
      sum += v.x + v.y + v.z + v.w;
#pragma unroll
      for (int e = 0; e < 4; ++e) {
        const unsigned u = __float_as_uint(vv[e]);
        h16[i * 4 + e] = (unsigned short)(u >> 16);
        const float hf = __uint_as_float(u & 0xffff0000u);
        l16[i * 4 + e] = (unsigned short)(__float_as_uint(vv[e] - hf) >> 16);
      }
    }
    unsigned short* dh = (unsigned short*)bhi + (size_t)row * NSP + t * 16;
    unsigned short* dl = (unsigned short*)blo + (size_t)row * NSP + t * 16;
    *(u16x8*)dh = *(u16x8*)&h16[0];
    *(u16x8*)(dh + 8) = *(u16x8*)&h16[8];
    *(u16x8*)dl = *(u16x8*)&l16[0];
    *(u16x8*)(dl + 8) = *(u16x8*)&l16[8];
#pragma unroll
    for (int off = 32; off; off >>= 1) sum += __shfl_down(sum, off);
    if (lane == 0) smem[wave] = sum;
    __syncthreads();
    if (t == 0) srow[row] = smem[0] + smem[1] + smem[2] + smem[3];
  } else if (idx < 2048) {
    // ---- cast a -> bf16 transposed: at[b][n][c] ----
    const int p = idx - 1024;
    const int n0 = (p & 63) * 64, c0 = ((p >> 6) & 3) * 64, b = p >> 8;
    float (*tile)[68] = (float(*)[68])smem;
    const int cr = t >> 4, nq = (t & 15) << 2;
    const float* src = a + ((size_t)(b * CCH + c0)) * NSP + n0;
#pragma unroll
    for (int s = 0; s < 4; ++s) {
      const float4 v = *(const float4*)(src + (size_t)(cr + s * 16) * NSP + nq);
      *(float4*)&tile[cr + s * 16][nq] = v;
    }
    __syncthreads();
    const int n = t >> 2, cq = (t & 3) << 4;
    __bf16 outv[16];
#pragma unroll
    for (int i = 0; i < 16; ++i) outv[i] = (__bf16)tile[cq + i][n];
    __bf16* dst = at + ((size_t)(b * NSP + n0 + n)) * CCH + c0 + cq;
    *(bf16x8*)dst = *(bf16x8*)&outv[0];
    *(bf16x8*)(dst + 8) = *(bf16x8*)&outv[8];
  } else if (idx < 2080) {
    // ---- prep: Wg = W_w @ g_w (z=0) ; PTt = theta_w^T @ phi_w (z=1) ----
    const int p = idx - 2048;
    const int zsel = p >> 4, rem = p & 15;
    const int m0 = (rem >> 2) * 64, n0 = (rem & 3) * 64;
    float (*As)[68] = (float(*)[68])smem;
    float (*Bs)[68] = (float(*)[68])(smem + 16 * 68);
    const int ty = t >> 4, tx = t & 15;
    float acc[4][4] = {};
    if (zsel == 0) {
      float4 ar = fetch_tr(W_w, CIN, m0, 0, t);
      float4 br = fetch_dir(g_w, CCH, 0, n0, t);
      for (int kt = 0; kt < 8; ++kt) {
        stash_tr(As, ar, t); stash_dir(Bs, br, t);
        __syncthreads();
        if (kt < 7) { ar = fetch_tr(W_w, CIN, m0, (kt + 1) * 16, t);
                      br = fetch_dir(g_w, CCH, (kt + 1) * 16, n0, t); }
        mm16(As, Bs, acc, ty, tx);
        __syncthreads();
      }
#pragma unroll
      for (int i = 0; i < 4; ++i) {
        const size_t off = (size_t)(m0 + (ty << 2) + i) * 256 + n0 + (tx << 2);
        *(float4*)(Wg + off) = make_float4(acc[i][0], acc[i][1], acc[i][2], acc[i][3]);
        __bf16 h4[4], l4[4];
#pragma unroll
        for (int j = 0; j < 4; ++j) {
          const __bf16 h = (__bf16)acc[i][j];
          h4[j] = h; l4[j] = (__bf16)(acc[i][j] - (float)h);
        }
        *(bf16x4*)(Wghi + off) = *(bf16x4*)h4;
        *(bf16x4*)(Wglo + off) = *(bf16x4*)l4;
      }
    } else {
      float4 ar = fetch_dir(theta_w, CCH, 0, m0, t);   // swapped: computes PT^T
      float4 br = fetch_dir(phi_w, CCH, 0, n0, t);
      for (int kt = 0; kt < 8; ++kt) {
        stash_dir(As, ar, t); stash_dir(Bs, br, t);
        __syncthreads();
        if (kt < 7) { ar = fetch_dir(theta_w, CCH, (kt + 1) * 16, m0, t);
                      br = fetch_dir(phi_w, CCH, (kt + 1) * 16, n0, t); }
        mm16(As, Bs, acc, ty, tx);
        __syncthreads();
      }
#pragma unroll
      for (int i = 0; i < 4; ++i) {
        const size_t off = (size_t)(m0 + (ty << 2) + i) * 256 + n0 + (tx << 2);
        __bf16 h4[4], l4[4];
#pragma unroll
        for (int j = 0; j < 4; ++j) {
          const __bf16 h = (__bf16)acc[i][j];
          h4[j] = h; l4[j] = (__bf16)(acc[i][j] - (float)h);
        }
        *(bf16x4*)(PTthi + off) = *(bf16x4*)h4;
        *(bf16x4*)(PTtlo + off) = *(bf16x4*)l4;
      }
    }
  } else if (idx == 2080) {
    // ---- vb[c] = phi_w^T @ theta_b ; d1 = phi_b . theta_b ----
    float* tb_s = smem;
    float* pb_s = smem + 128;
    if (t < 128) { tb_s[t] = theta_b[t]; pb_s[t] = phi_b[t]; }
    __syncthreads();
    float acc = 0.f;
#pragma unroll 8
    for (int i = 0; i < 128; ++i) acc += phi_w[(size_t)i * 256 + t] * tb_s[i];
    vb_g[t] = acc;
    if (t < 64) {
      float pv = pb_s[t] * tb_s[t] + pb_s[t + 64] * tb_s[t + 64];
      pv = wave_reduce(pv);
      if (t == 0) dvec[0] = pv;
    }
  } else if (idx == 2081) {
    // ---- vpt[c] = phi_b^T @ theta_w ----
    float* pb_s = smem;
    if (t < 128) pb_s[t] = phi_b[t];
    __syncthreads();
    float acc = 0.f;
#pragma unroll 8
    for (int i = 0; i < 128; ++i) acc += pb_s[i] * theta_w[(size_t)i * 256 + t];
    vpt[t] = acc;
  } else {
    // ---- wgb[o] = W_w[o] . g_b : 4 blocks x 64 outputs ----
    const int p = idx - 2082;
    float* gb_s = smem;
    if (t < 128) gb_s[t] = g_b[t];
    __syncthreads();
    const float2 gv = *(const float2*)&gb_s[lane * 2];
    for (int i = 0; i < 16; ++i) {
      const int o = p * 64 + wave * 16 + i;
      const float2 r = *(const float2*)(W_w + (size_t)o * 128 + lane * 2);
      float v = fmaf(r.x, gv.x, r.y * gv.y);
      v = wave_reduce(v);
      if (lane == 0) wgb[o] = v;
    }
  }
}

// ===== k1: gram partials as pure bf16 MFMA GEMM (no conversion VALU) ============
__global__ __launch_bounds__(256) void gram_kernel(
    const __bf16* __restrict__ bhi, const __bf16* __restrict__ blo,
    float* __restrict__ Gpart) {
  const int idx = blockIdx.x;
  const int t = threadIdx.x;
  const int wave = t >> 6, lane = t & 63;
  const int jt = idx & 3, it = (idx >> 2) & 3;
  const int z = idx >> 4, batch = z >> 4, kc = z & 15;
  const int m = lane & 15, q = lane >> 4;
  const size_t base = (size_t)batch * CCH * NSP;
  const __bf16* ah_p = bhi + base + (size_t)(it * 64 + wave * 16 + m) * NSP + kc * 256 + q * 8;
  const __bf16* al_p = blo + base + (size_t)(it * 64 + wave * 16 + m) * NSP + kc * 256 + q * 8;
  const __bf16* bh_p = bhi + base + (size_t)(jt * 64 + m) * NSP + kc * 256 + q * 8;
  const __bf16* bl_p = blo + base + (size_t)(jt * 64 + m) * NSP + kc * 256 + q * 8;
  f32x4 acc[4] = {};
#pragma unroll
  for (int ks = 0; ks < 8; ++ks) {
    const int k = ks * 32;
    const bf16x8 ah = *(const bf16x8*)(ah_p + k);
    const bf16x8 al = *(const bf16x8*)(al_p + k);
#pragma unroll
    for (int t4 = 0; t4 < 4; ++t4) {
      const bf16x8 bh = *(const bf16x8*)(bh_p + (size_t)t4 * 16 * NSP + k);
      const bf16x8 bl = *(const bf16x8*)(bl_p + (size_t)t4 * 16 * NSP + k);
      acc[t4] = __builtin_amdgcn_mfma_f32_16x16x32_bf16(ah, bh, acc[t4], 0, 0, 0);
      acc[t4] = __builtin_amdgcn_mfma_f32_16x16x32_bf16(ah, bl, acc[t4], 0, 0, 0);
      acc[t4] = __builtin_amdgcn_mfma_f32_16x16x32_bf16(al, bh, acc[t4], 0, 0, 0);
    }
  }
  float* Gp = Gpart + ((size_t)(kc * 4 + batch)) * 65536;
#pragma unroll
  for (int t4 = 0; t4 < 4; ++t4)
#pragma unroll
    for (int r = 0; r < 4; ++r)
      Gp[(size_t)(it * 64 + wave * 16 + q * 4 + r) * 256 + jt * 64 + t4 * 16 + m] =
          acc[t4][r];
}

// ===== k2: fused reduce+W2, 1x Gpart read (blocks 0..63) + aux (64..127) ========
__global__ __launch_bounds__(256) void redw2_kernel(
    const float* __restrict__ Gpart, const float* __restrict__ vb_g,
    float* __restrict__ t2_g, const float* __restrict__ srow,
    const float* __restrict__ Wg,
    const __bf16* __restrict__ Wghi, const __bf16* __restrict__ Wglo,
    const __bf16* __restrict__ PTthi, const __bf16* __restrict__ PTtlo,
    __bf16* __restrict__ W2hi, __bf16* __restrict__ W2lo,
    float* __restrict__ Wgs, float* __restrict__ sPTv, float* __restrict__ dvec) {
  const int blk = blockIdx.x;
  const int t = threadIdx.x;
  const int wave = t >> 6, lane = t & 63;
  __shared__ __bf16 Gsh[16][264], Gsl[16][264];   // +8 pad: 2-way banks only
  __shared__ float lds[256];
  if (blk < 64) {
    const int b = blk >> 4, nt = blk & 15;
    // ---- phase A: reduce 16 rows x 256 cols over 16 partials (read once) ----
    const int rr = t >> 4;
    const int c0 = (t & 15) * 16;
    f32x4 s[4] = {};
#pragma unroll
    for (int p = 0; p < 16; ++p) {
      const float* src = Gpart + (((size_t)(p * 4 + b)) << 16) +
                         (size_t)(nt * 16 + rr) * 256 + c0;
#pragma unroll
      for (int e = 0; e < 4; ++e) s[e] += *(const f32x4*)(src + e * 4);
    }
    {
      float part = 0.f;
#pragma unroll
      for (int e = 0; e < 4; ++e) {
        const float4 vv = *(const float4*)(vb_g + c0 + e * 4);
        part += s[e][0] * vv.x + s[e][1] * vv.y + s[e][2] * vv.z + s[e][3] * vv.w;
      }
#pragma unroll
      for (int off = 8; off; off >>= 1) part += __shfl_down(part, off);
      if ((t & 15) == 0) t2_g[b * 256 + nt * 16 + rr] = part;
    }
    __bf16 h8[16], l8[16];
#pragma unroll
    for (int e = 0; e < 16; ++e) {
      const float x = s[e >> 2][e & 3];
      const __bf16 h = (__bf16)x;
      h8[e] = h; l8[e] = (__bf16)(x - (float)h);
    }
    *(bf16x8*)&Gsh[rr][c0] = *(bf16x8*)&h8[0];
    *(bf16x8*)&Gsh[rr][c0 + 8] = *(bf16x8*)&h8[8];
    *(bf16x8*)&Gsl[rr][c0] = *(bf16x8*)&l8[0];
    *(bf16x8*)&Gsl[rr][c0 + 8] = *(bf16x8*)&l8[8];
    __syncthreads();
    // ---- phase B: 4 independent W2 tiles per wave (mt = i*4 + wave) ----
    const int m = lane & 15, q = lane >> 4;
    f32x4 acc[4] = {};
#pragma unroll
    for (int ks = 0; ks < 8; ++ks) {
      const int k = ks * 32 + q * 8;
      const bf16x8 bh = *(const bf16x8*)&Gsh[m][k];
      const bf16x8 bl = *(const bf16x8*)&Gsl[m][k];
#pragma unroll
      for (int i = 0; i < 4; ++i) {
        const int mt = i * 4 + wave;
        const bf16x8 ah = *(const bf16x8*)(Wghi + (size_t)(mt * 16 + m) * 256 + k);
        const bf16x8 al = *(const bf16x8*)(Wglo + (size_t)(mt * 16 + m) * 256 + k);
        acc[i] = __builtin_amdgcn_mfma_f32_16x16x32_bf16(ah, bh, acc[i], 0, 0, 0);
        acc[i] = __builtin_amdgcn_mfma_f32_16x16x32_bf16(ah, bl, acc[i], 0, 0, 0);
        acc[i] = __builtin_amdgcn_mfma_f32_16x16x32_bf16(al, bh, acc[i], 0, 0, 0);
      }
    }
#pragma unroll
    for (int i = 0; i < 4; ++i) {
      const int mt = i * 4 + wave;
#pragma unroll
      for (int r = 0; r < 4; ++r) {
        const size_t off = ((size_t)b << 16) + (size_t)(mt * 16 + q * 4 + r) * 256 +
                           nt * 16 + m;
        const float v = acc[i][r];
        const __bf16 h = (__bf16)v;
        W2hi[off] = h;
        W2lo[off] = (__bf16)(v - (float)h);
      }
    }
  } else {
    // ---- aux: Wgs = Wg@s ; sPTv = PTt@s ; d2 = s.vb ----
    const int p = blk - 64;
    const int b = p >> 4, seg = p & 15;
    lds[t] = srow[b * 256 + t];
    __syncthreads();
    const float4 sv = *(const float4*)&lds[lane * 4];
    for (int i = wave; i < 16; i += 4) {
      const int o = seg * 16 + i;
      const float4 r = *(const float4*)(Wg + (size_t)o * 256 + lane * 4);
      float v = fmaf(r.x, sv.x, fmaf(r.y, sv.y, fmaf(r.z, sv.z, r.w * sv.w)));
      v = wave_reduce(v);
      if (lane == 0) Wgs[b * 256 + o] = v;
    }
    for (int i = wave; i < 16; i += 4) {
      const int c = seg * 16 + i;
      const bf16x4 ph = *(const bf16x4*)(PTthi + (size_t)c * 256 + lane * 4);
      const bf16x4 pl = *(const bf16x4*)(PTtlo + (size_t)c * 256 + lane * 4);
      const float svv[4] = {sv.x, sv.y, sv.z, sv.w};
      float v = 0.f;
#pragma unroll
      for (int e = 0; e < 4; ++e) v += ((float)ph[e] + (float)pl[e]) * svv[e];
      v = wave_reduce(v);
      if (lane == 0) sPTv[b * 256 + c] = v;
    }
    if (seg == 0 && wave == 0) {
      const float4 vbv = *(const float4*)(vb_g + lane * 4);
      float v = fmaf(vbv.x, sv.x, fmaf(vbv.y, sv.y, fmaf(vbv.z, sv.z, vbv.w * sv.w)));
      v = wave_reduce(v);
      if (lane == 0) dvec[1 + b] = v;
    }
  }
}

// ===== k3: W_out (blocks 0..63, 4 tiles/wave) + bias chain (64..79) =============
__global__ __launch_bounds__(256) void wout_mfma_kernel(
    const __bf16* __restrict__ W2hi, const __bf16* __restrict__ W2lo,
    const __bf16* __restrict__ PTthi, const __bf16* __restrict__ PTtlo,
    const float* __restrict__ Wgs, const float* __restrict__ sPT,
    const float* __restrict__ wgb, const float* __restrict__ vpt,
    const float* __restrict__ Wg, const float* __restrict__ t2_g,
    const float* __restrict__ dvec,
    const float* __restrict__ bn_gamma, const float* __restrict__ bn_beta,
    const float* __restrict__ bn_mean, const float* __restrict__ bn_var,
    __bf16* __restrict__ Whi, __bf16* __restrict__ Wlo,
    float* __restrict__ bias_out) {
  const int blk = blockIdx.x;
  const int t = threadIdx.x;
  const int wave = t >> 6, lane = t & 63;
  if (blk < 64) {
    const int batch = blk >> 4, nt = blk & 15;
    const int m = lane & 15, q = lane >> 4;
    const __bf16* bh_p = PTthi + (size_t)(nt * 16 + m) * 256;   // PTt row = PT column
    const __bf16* bl_p = PTtlo + (size_t)(nt * 16 + m) * 256;
    const __bf16* w2h = W2hi + (size_t)batch * 65536;
    const __bf16* w2l = W2lo + (size_t)batch * 65536;
    f32x4 acc[4] = {};
#pragma unroll
    for (int ks = 0; ks < 8; ++ks) {
      const int k = ks * 32 + q * 8;
      const bf16x8 bh = *(const bf16x8*)(bh_p + k);
      const bf16x8 bl = *(const bf16x8*)(bl_p + k);
#pragma unroll
      for (int i = 0; i < 4; ++i) {
        const int mt = i * 4 + wave;
        const bf16x8 ah = *(const bf16x8*)(w2h + (size_t)(mt * 16 + m) * 256 + k);
        const bf16x8 al = *(const bf16x8*)(w2l + (size_t)(mt * 16 + m) * 256 + k);
        acc[i] = __builtin_amdgcn_mfma_f32_16x16x32_bf16(ah, bh, acc[i], 0, 0, 0);
        acc[i] = __builtin_amdgcn_mfma_f32_16x16x32_bf16(ah, bl, acc[i], 0, 0, 0);
        acc[i] = __builtin_amdgcn_mfma_f32_16x16x32_bf16(al, bh, acc[i], 0, 0, 0);
      }
    }
    const float invN = 1.0f / 4096.0f;
    const int c = nt * 16 + m;
    const float vpt_c = vpt[c];
    const float sPT_c = sPT[batch * 256 + c];
#pragma unroll
    for (int i = 0; i < 4; ++i) {
      const int mt = i * 4 + wave;
#pragma unroll
      for (int r = 0; r < 4; ++r) {
        const int o = mt * 16 + q * 4 + r;
        const float sc = bn_gamma[o] * rsqrtf(bn_var[o] + BN_EPS);
        const float w = sc * ((acc[i][r] + Wgs[batch * 256 + o] * vpt_c + wgb[o] * sPT_c) * invN +
                              wgb[o] * vpt_c);
        const size_t off = (size_t)batch * 65536 + (size_t)o * 256 + c;
        const __bf16 h = (__bf16)w;
        Whi[off] = h;
        Wlo[off] = (__bf16)(w - (float)h);
      }
    }
  } else {
    // ---- bias chain: bias = sc*((Wg@t2 + Wgs*d1 + wgb*(d2+N*d1))/N - mean)+beta
    const int p = blk - 64;
    const int b = p >> 2, quarter = p & 3;
    __shared__ float t2s[256];
    t2s[t] = t2_g[b * 256 + t];
    __syncthreads();
    const float d1 = dvec[0], d2 = dvec[1 + b];
    const float invN = 1.0f / 4096.0f;
    const float4 tv = *(const float4*)&t2s[lane * 4];
    for (int it = 0; it < 16; ++it) {
      const int o = quarter * 64 + wave * 16 + it;
      const float4 r = *(const float4*)(Wg + (size_t)o * 256 + lane * 4);
      float v = fmaf(r.x, tv.x, fmaf(r.y, tv.y, fmaf(r.z, tv.z, r.w * tv.w)));
      v = wave_reduce(v);
      if (lane == 0) {
        const float bias_full = (v + Wgs[b * 256 + o] * d1 +
                                 wgb[o] * (d2 + 4096.0f * d1)) * invN;
        const float sc = bn_gamma[o] * rsqrtf(bn_var[o] + BN_EPS);
        bias_out[b * 256 + o] = sc * (bias_full - bn_mean[o]) + bn_beta[o];
      }
    }
  }
}

// ===== k4: out[b] = W_out[b] @ a[b] + bias (64x64 per block, 4 acc chains) ======
__global__ __launch_bounds__(256) void out_mfma_kernel(const __bf16* __restrict__ Whi,
                                                       const __bf16* __restrict__ Wlo,
                                                       const __bf16* __restrict__ at,
                                                       const float* __restrict__ bias_out,
                                                       float* __restrict__ out) {
  const int nt = blockIdx.x, mt = blockIdx.y, b = blockIdx.z;
  const int wave = threadIdx.x >> 6, lane = threadIdx.x & 63;
  const int m = lane & 15, q = lane >> 4;
  const int o = mt * 64 + wave * 16 + m;
  const __bf16* wh = Whi + (size_t)b * 65536 + (size_t)o * 256;
  const __bf16* wl = Wlo + (size_t)b * 65536 + (size_t)o * 256;
  const __bf16* atb = at + ((size_t)b * NSP + nt * 64) * CCH;
  f32x4 acc[4] = {};
#pragma unroll
  for (int ks = 0; ks < 8; ++ks) {
    const int k = ks * 32 + q * 8;
    const bf16x8 ah = *(const bf16x8*)(wh + k);
    const bf16x8 al = *(const bf16x8*)(wl + k);
#pragma unroll
    for (int t4 = 0; t4 < 4; ++t4) {
      const bf16x8 bh = *(const bf16x8*)(atb + (size_t)(t4 * 16 + m) * 256 + k);
      acc[t4] = __builtin_amdgcn_mfma_f32_16x16x32_bf16(ah, bh, acc[t4], 0, 0, 0);
      acc[t4] = __builtin_amdgcn_mfma_f32_16x16x32_bf16(al, bh, acc[t4], 0, 0, 0);
    }
  }
  float* ob = out + (size_t)b * CCH * NSP;
#pragma unroll
  for (int r = 0; r < 4; ++r) {
    const int orow = mt * 64 + wave * 16 + q * 4 + r;
    const float bo = bias_out[b * 256 + orow];
#pragma unroll
    for (int t4 = 0; t4 < 4; ++t4)
      ob[(size_t)orow * NSP + nt * 64 + t4 * 16 + m] = acc[t4][r] + bo;
  }
}

extern "C" void kernel_launch(void* const* d_in, const int* in_sizes, int n_in,
                              void* d_out, int out_size, void* d_ws, size_t ws_size,
                              hipStream_t stream) {
  (void)in_sizes; (void)n_in; (void)out_size; (void)ws_size;
  const float* a       = (const float*)d_in[0];
  const float* bI      = (const float*)d_in[1];
  const float* theta_w = (const float*)d_in[2];
  const float* theta_b = (const float*)d_in[3];
  const float* phi_w   = (const float*)d_in[4];
  const float* phi_b   = (const float*)d_in[5];
  const float* g_w     = (const float*)d_in[6];
  const float* g_b     = (const float*)d_in[7];
  const float* W_w     = (const float*)d_in[8];
  const float* bn_gamma= (const float*)d_in[9];
  const float* bn_beta = (const float*)d_in[10];
  const float* bn_mean = (const float*)d_in[11];
  const float* bn_var  = (const float*)d_in[12];
  float* out = (float*)d_out;
  float* ws  = (float*)d_ws;

  // fp32 region (float offsets)
  float* Gpart    = ws;                  // 4194304 (16 MB)
  float* srow     = ws + 4194304;        // 1024
  float* Wg       = ws + 4195328;        // 65536
  float* bias_out = ws + 4260864;        // 1024
  float* Wgs      = ws + 4261888;        // 1024
  float* sPTv     = ws + 4262912;        // 1024
  float* wgb      = ws + 4263936;        // 256
  float* vpt      = ws + 4264192;        // 256
  float* vb_g     = ws + 4264448;        // 256
  float* t2_g     = ws + 4264704;        // 1024
  float* dvec     = ws + 4265728;        // 8 (pad to 256)
  // bf16 region
  __bf16* at    = (__bf16*)(ws + 4265984);   // 8 MB
  __bf16* Wghi  = (__bf16*)(ws + 6363136);   // 128 KB each below
  __bf16* Wglo  = (__bf16*)(ws + 6395904);
  __bf16* PTthi = (__bf16*)(ws + 6428672);
  __bf16* PTtlo = (__bf16*)(ws + 6461440);
  __bf16* W2hi  = (__bf16*)(ws + 6494208);   // 512 KB each below
  __bf16* W2lo  = (__bf16*)(ws + 6625280);
  __bf16* Whi   = (__bf16*)(ws + 6756352);
  __bf16* Wlo   = (__bf16*)(ws + 6887424);
  __bf16* bhi   = (__bf16*)(ws + 7018496);   // 8 MB
  __bf16* blo   = (__bf16*)(ws + 9115648);   // 8 MB, end ~44.9 MB

  prep_kernel<<<dim3(2086), dim3(256), 0, stream>>>(bI, a, W_w, g_w, phi_w, theta_w,
                                                    phi_b, theta_b, g_b,
                                                    bhi, blo, srow, Wg, Wghi, Wglo,
                                                    PTthi, PTtlo, at,
                                                    vb_g, vpt, wgb, dvec);
  gram_kernel<<<dim3(1024), dim3(256), 0, stream>>>(bhi, blo, Gpart);
  redw2_kernel<<<dim3(128), dim3(256), 0, stream>>>(Gpart, vb_g, t2_g, srow, Wg,
                                                    Wghi, Wglo, PTthi, PTtlo,
                                                    W2hi, W2lo, Wgs, sPTv, dvec);
  wout_mfma_kernel<<<dim3(80), dim3(256), 0, stream>>>(W2hi, W2lo, PTthi, PTtlo,
                                                       Wgs, sPTv, wgb, vpt, Wg, t2_g,
                                                       dvec, bn_gamma, bn_beta, bn_mean,
                                                       bn_var, Whi, Wlo, bias_out);
  out_mfma_kernel<<<dim3(64, 4, 4), dim3(256), 0, stream>>>(Whi, Wlo, at, bias_out, out);
}

// Round 2
// 184.136 us; speedup vs baseline: 1.1055x; 1.1055x over previous
//
#include <hip/hip_runtime.h>
#include <hip/hip_bf16.h>

#define NSP 4096   // H*W
#define CCH 256    // C
#define CIN 128    // Ci
#define BN_EPS 1e-5f

typedef __bf16 bf16x8 __attribute__((ext_vector_type(8)));
typedef __bf16 bf16x4 __attribute__((ext_vector_type(4)));
typedef float f32x4 __attribute__((ext_vector_type(4)));
typedef unsigned short u16x8 __attribute__((ext_vector_type(8)));

typedef const __attribute__((address_space(1))) unsigned int gu32;
typedef __attribute__((address_space(3))) unsigned int lu32;

// ================= fp32 tile helpers (prep only) =================================

__device__ __forceinline__ float4 fetch_tr(const float* __restrict__ A, int lda, int m0,
                                           int k0, int tid) {
  const int r = tid >> 2, kq = (tid & 3) << 2;
  return *(const float4*)(A + (size_t)(m0 + r) * lda + k0 + kq);
}
__device__ __forceinline__ void stash_tr(float (*As)[68], float4 v, int tid) {
  const int r = tid >> 2, kq = (tid & 3) << 2;
  As[kq + 0][r] = v.x; As[kq + 1][r] = v.y; As[kq + 2][r] = v.z; As[kq + 3][r] = v.w;
}
__device__ __forceinline__ float4 fetch_dir(const float* __restrict__ B, int ldb, int k0,
                                            int n0, int tid) {
  const int kr = tid >> 4, nq = (tid & 15) << 2;
  return *(const float4*)(B + (size_t)(k0 + kr) * ldb + n0 + nq);
}
__device__ __forceinline__ void stash_dir(float (*Bs)[68], float4 v, int tid) {
  const int kr = tid >> 4, nq = (tid & 15) << 2;
  *(float4*)(&Bs[kr][nq]) = v;
}

__device__ __forceinline__ void mm16(const float (*As)[68], const float (*Bs)[68],
                                     float acc[4][4], int ty, int tx) {
#pragma unroll
  for (int kk = 0; kk < 16; ++kk) {
    const float4 av = *(const float4*)(&As[kk][ty << 2]);
    const float4 bv = *(const float4*)(&Bs[kk][tx << 2]);
    const float ar[4] = {av.x, av.y, av.z, av.w};
    const float br[4] = {bv.x, bv.y, bv.z, bv.w};
#pragma unroll
    for (int i = 0; i < 4; ++i)
#pragma unroll
      for (int j = 0; j < 4; ++j) acc[i][j] += ar[i] * br[j];
  }
}

__device__ __forceinline__ float wave_reduce(float v) {
#pragma unroll
  for (int off = 32; off; off >>= 1) v += __shfl_down(v, off);
  return v;  // valid in lane 0
}

// ===== k0: all independent prep in one dispatch =================================
// cast_b+srow(0..1023) + cast_a(1024..2047) + prep(2048..2079) + vb/d1(2080)
// + vpt(2081) + wgb(2082..2085)
__global__ __launch_bounds__(256) void prep_kernel(
    const float* __restrict__ bin, const float* __restrict__ a,
    const float* __restrict__ W_w, const float* __restrict__ g_w,
    const float* __restrict__ phi_w, const float* __restrict__ theta_w,
    const float* __restrict__ phi_b, const float* __restrict__ theta_b,
    const float* __restrict__ g_b,
    __bf16* __restrict__ bhi, __bf16* __restrict__ blo,
    float* __restrict__ srow,
    float* __restrict__ Wg, __bf16* __restrict__ Wghi, __bf16* __restrict__ Wglo,
    __bf16* __restrict__ PTthi, __bf16* __restrict__ PTtlo,
    __bf16* __restrict__ at,
    float* __restrict__ vb_g, float* __restrict__ vpt, float* __restrict__ wgb,
    float* __restrict__ dvec) {
  __shared__ float smem[64 * 68];
  const int idx = blockIdx.x;
  const int t = threadIdx.x;
  const int wave = t >> 6, lane = t & 63;
  if (idx < 1024) {
    // ---- cast b -> bf16 hi/lo (truncation, identical to old f8_hilo) + exact srow
    const int row = idx;  // global row over 4*256
    const float* src = bin + (size_t)row * NSP + t * 16;
    float sum = 0.f;
    unsigned short h16[16], l16[16];
#pragma unroll
    for (int i = 0; i < 4; ++i) {
      const float4 v = *(const float4*)(src + i * 4);
      const float vv[4] = {v.x, v.y, v.z, v.w};
      sum += v.x + v.y + v.z + v.w;
#pragma unroll
      for (int e = 0; e < 4; ++e) {
        const unsigned u = __float_as_uint(vv[e]);
        h16[i * 4 + e] = (unsigned short)(u >> 16);
        const float hf = __uint_as_float(u & 0xffff0000u);
        l16[i * 4 + e] = (unsigned short)(__float_as_uint(vv[e] - hf) >> 16);
      }
    }
    unsigned short* dh = (unsigned short*)bhi + (size_t)row * NSP + t * 16;
    unsigned short* dl = (unsigned short*)blo + (size_t)row * NSP + t * 16;
    *(u16x8*)dh = *(u16x8*)&h16[0];
    *(u16x8*)(dh + 8) = *(u16x8*)&h16[8];
    *(u16x8*)dl = *(u16x8*)&l16[0];
    *(u16x8*)(dl + 8) = *(u16x8*)&l16[8];
#pragma unroll
    for (int off = 32; off; off >>= 1) sum += __shfl_down(sum, off);
    if (lane == 0) smem[wave] = sum;
    __syncthreads();
    if (t == 0) srow[row] = smem[0] + smem[1] + smem[2] + smem[3];
  } else if (idx < 2048) {
    // ---- cast a -> bf16 transposed: at[b][n][c] ----
    const int p = idx - 1024;
    const int n0 = (p & 63) * 64, c0 = ((p >> 6) & 3) * 64, b = p >> 8;
    float (*tile)[68] = (float(*)[68])smem;
    const int cr = t >> 4, nq = (t & 15) << 2;
    const float* src = a + ((size_t)(b * CCH + c0)) * NSP + n0;
#pragma unroll
    for (int s = 0; s < 4; ++s) {
      const float4 v = *(const float4*)(src + (size_t)(cr + s * 16) * NSP + nq);
      *(float4*)&tile[cr + s * 16][nq] = v;
    }
    __syncthreads();
    const int n = t >> 2, cq = (t & 3) << 4;
    __bf16 outv[16];
#pragma unroll
    for (int i = 0; i < 16; ++i) outv[i] = (__bf16)tile[cq + i][n];
    __bf16* dst = at + ((size_t)(b * NSP + n0 + n)) * CCH + c0 + cq;
    *(bf16x8*)dst = *(bf16x8*)&outv[0];
    *(bf16x8*)(dst + 8) = *(bf16x8*)&outv[8];
  } else if (idx < 2080) {
    // ---- prep: Wg = W_w @ g_w (z=0) ; PTt = theta_w^T @ phi_w (z=1) ----
    const int p = idx - 2048;
    const int zsel = p >> 4, rem = p & 15;
    const int m0 = (rem >> 2) * 64, n0 = (rem & 3) * 64;
    float (*As)[68] = (float(*)[68])smem;
    float (*Bs)[68] = (float(*)[68])(smem + 16 * 68);
    const int ty = t >> 4, tx = t & 15;
    float acc[4][4] = {};
    if (zsel == 0) {
      float4 ar = fetch_tr(W_w, CIN, m0, 0, t);
      float4 br = fetch_dir(g_w, CCH, 0, n0, t);
      for (int kt = 0; kt < 8; ++kt) {
        stash_tr(As, ar, t); stash_dir(Bs, br, t);
        __syncthreads();
        if (kt < 7) { ar = fetch_tr(W_w, CIN, m0, (kt + 1) * 16, t);
                      br = fetch_dir(g_w, CCH, (kt + 1) * 16, n0, t); }
        mm16(As, Bs, acc, ty, tx);
        __syncthreads();
      }
#pragma unroll
      for (int i = 0; i < 4; ++i) {
        const size_t off = (size_t)(m0 + (ty << 2) + i) * 256 + n0 + (tx << 2);
        *(float4*)(Wg + off) = make_float4(acc[i][0], acc[i][1], acc[i][2], acc[i][3]);
        __bf16 h4[4], l4[4];
#pragma unroll
        for (int j = 0; j < 4; ++j) {
          const __bf16 h = (__bf16)acc[i][j];
          h4[j] = h; l4[j] = (__bf16)(acc[i][j] - (float)h);
        }
        *(bf16x4*)(Wghi + off) = *(bf16x4*)h4;
        *(bf16x4*)(Wglo + off) = *(bf16x4*)l4;
      }
    } else {
      float4 ar = fetch_dir(theta_w, CCH, 0, m0, t);   // swapped: computes PT^T
      float4 br = fetch_dir(phi_w, CCH, 0, n0, t);
      for (int kt = 0; kt < 8; ++kt) {
        stash_dir(As, ar, t); stash_dir(Bs, br, t);
        __syncthreads();
        if (kt < 7) { ar = fetch_dir(theta_w, CCH, (kt + 1) * 16, m0, t);
                      br = fetch_dir(phi_w, CCH, (kt + 1) * 16, n0, t); }
        mm16(As, Bs, acc, ty, tx);
        __syncthreads();
      }
#pragma unroll
      for (int i = 0; i < 4; ++i) {
        const size_t off = (size_t)(m0 + (ty << 2) + i) * 256 + n0 + (tx << 2);
        __bf16 h4[4], l4[4];
#pragma unroll
        for (int j = 0; j < 4; ++j) {
          const __bf16 h = (__bf16)acc[i][j];
          h4[j] = h; l4[j] = (__bf16)(acc[i][j] - (float)h);
        }
        *(bf16x4*)(PTthi + off) = *(bf16x4*)h4;
        *(bf16x4*)(PTtlo + off) = *(bf16x4*)l4;
      }
    }
  } else if (idx == 2080) {
    // ---- vb[c] = phi_w^T @ theta_b ; d1 = phi_b . theta_b ----
    float* tb_s = smem;
    float* pb_s = smem + 128;
    if (t < 128) { tb_s[t] = theta_b[t]; pb_s[t] = phi_b[t]; }
    __syncthreads();
    float acc = 0.f;
#pragma unroll 8
    for (int i = 0; i < 128; ++i) acc += phi_w[(size_t)i * 256 + t] * tb_s[i];
    vb_g[t] = acc;
    if (t < 64) {
      float pv = pb_s[t] * tb_s[t] + pb_s[t + 64] * tb_s[t + 64];
      pv = wave_reduce(pv);
      if (t == 0) dvec[0] = pv;
    }
  } else if (idx == 2081) {
    // ---- vpt[c] = phi_b^T @ theta_w ----
    float* pb_s = smem;
    if (t < 128) pb_s[t] = phi_b[t];
    __syncthreads();
    float acc = 0.f;
#pragma unroll 8
    for (int i = 0; i < 128; ++i) acc += pb_s[i] * theta_w[(size_t)i * 256 + t];
    vpt[t] = acc;
  } else {
    // ---- wgb[o] = W_w[o] . g_b : 4 blocks x 64 outputs ----
    const int p = idx - 2082;
    float* gb_s = smem;
    if (t < 128) gb_s[t] = g_b[t];
    __syncthreads();
    const float2 gv = *(const float2*)&gb_s[lane * 2];
    for (int i = 0; i < 16; ++i) {
      const int o = p * 64 + wave * 16 + i;
      const float2 r = *(const float2*)(W_w + (size_t)o * 128 + lane * 2);
      float v = fmaf(r.x, gv.x, r.y * gv.y);
      v = wave_reduce(v);
      if (lane == 0) wgb[o] = v;
    }
  }
}

// ===== k1: gram partials — LDS-staged bf16 MFMA GEMM (global_load_lds, dbuf) ====
// Per block (jt,it,kc,batch): G_tile[64x64] += A(64 rows) x B(64 rows)^T over k=256.
// LDS tiles hold a 32-k slab as 8 chunks/row of 16B: chunk ch = (h*4 + j) ^ (r&7)
// (h: 0=hi 1=lo, j: k-quad). Swizzle applied on the per-lane GLOBAL source address
// (LDS dest of global_load_lds is linear wave-uniform-base + lane*16), and undone
// identically on the ds_read side -> banks balanced, numerics bit-identical.
__global__ __launch_bounds__(256) void gram_kernel(
    const __bf16* __restrict__ bhi, const __bf16* __restrict__ blo,
    float* __restrict__ Gpart) {
  __shared__ __bf16 At[2][64][64];
  __shared__ __bf16 Bt[2][64][64];
  const int idx = blockIdx.x;
  const int t = threadIdx.x;
  const int wave = t >> 6, lane = t & 63;
  const int jt = idx & 3, it = (idx >> 2) & 3;
  const int z = idx >> 4, batch = z >> 4, kc = z & 15;
  const int m = lane & 15, q = lane >> 4;
  const size_t rowbase = (size_t)batch * CCH;
  const int colbase = kc * 256;
  // staging lane geometry (constant per lane): r_in_seg, chunk, unswizzled (h,j)
  const int rseg = lane >> 3, ch = lane & 7;
  const int u = ch ^ rseg;          // r&7 == rseg since segments are 8-row aligned
  const int h = u >> 2, j = u & 3;
  const __bf16* gsrc = h ? blo : bhi;

  auto stage = [&](int ph, int ks) {
#pragma unroll
    for (int c = 0; c < 4; ++c) {
      const int s = wave * 4 + c;       // 0..15: 0-7 A-tile KBs, 8-15 B-tile KBs
      const int isB = s >> 3;
      const int kb = s & 7;
      const int grow = (isB ? jt : it) * 64 + kb * 8 + rseg;
      const __bf16* gp = gsrc + (rowbase + (size_t)grow) * NSP +
                         colbase + ks * 32 + j * 8;
      const __bf16* lp = isB ? &Bt[ph][kb * 8][0] : &At[ph][kb * 8][0];
      __builtin_amdgcn_global_load_lds((gu32*)(const void*)gp,
                                       (lu32*)(void*)lp, 16, 0, 0);
    }
  };

  f32x4 acc[4] = {};
  const int chA = q ^ (m & 7);        // hi chunk for this lane's rows (r&7 == m&7)
  stage(0, 0);
  int ph = 0;
  for (int ks = 0; ks < 8; ++ks) {
    __syncthreads();                  // stage(ks) visible (vmcnt drained at barrier)
    if (ks < 7) stage(ph ^ 1, ks + 1);
    const bf16x8 ah = *(const bf16x8*)&At[ph][wave * 16 + m][chA * 8];
    const bf16x8 al = *(const bf16x8*)&At[ph][wave * 16 + m][(chA ^ 4) * 8];
#pragma unroll
    for (int t4 = 0; t4 < 4; ++t4) {
      const bf16x8 bh = *(const bf16x8*)&Bt[ph][t4 * 16 + m][chA * 8];
      const bf16x8 bl = *(const bf16x8*)&Bt[ph][t4 * 16 + m][(chA ^ 4) * 8];
      acc[t4] = __builtin_amdgcn_mfma_f32_16x16x32_bf16(ah, bh, acc[t4], 0, 0, 0);
      acc[t4] = __builtin_amdgcn_mfma_f32_16x16x32_bf16(ah, bl, acc[t4], 0, 0, 0);
      acc[t4] = __builtin_amdgcn_mfma_f32_16x16x32_bf16(al, bh, acc[t4], 0, 0, 0);
    }
    ph ^= 1;
  }
  float* Gp = Gpart + ((size_t)(kc * 4 + batch)) * 65536;
#pragma unroll
  for (int t4 = 0; t4 < 4; ++t4)
#pragma unroll
    for (int r = 0; r < 4; ++r)
      Gp[(size_t)(it * 64 + wave * 16 + q * 4 + r) * 256 + jt * 64 + t4 * 16 + m] =
          acc[t4][r];
}

// ===== k2: fused reduce+W2, 1x Gpart read (blocks 0..63) + aux (64..127) ========
__global__ __launch_bounds__(256) void redw2_kernel(
    const float* __restrict__ Gpart, const float* __restrict__ vb_g,
    float* __restrict__ t2_g, const float* __restrict__ srow,
    const float* __restrict__ Wg,
    const __bf16* __restrict__ Wghi, const __bf16* __restrict__ Wglo,
    const __bf16* __restrict__ PTthi, const __bf16* __restrict__ PTtlo,
    __bf16* __restrict__ W2hi, __bf16* __restrict__ W2lo,
    float* __restrict__ Wgs, float* __restrict__ sPTv, float* __restrict__ dvec) {
  const int blk = blockIdx.x;
  const int t = threadIdx.x;
  const int wave = t >> 6, lane = t & 63;
  __shared__ __bf16 Gsh[16][264], Gsl[16][264];   // +8 pad: 2-way banks only
  __shared__ float lds[256];
  if (blk < 64) {
    const int b = blk >> 4, nt = blk & 15;
    // ---- phase A: reduce 16 rows x 256 cols over 16 partials (read once) ----
    const int rr = t >> 4;
    const int c0 = (t & 15) * 16;
    f32x4 s[4] = {};
#pragma unroll
    for (int p = 0; p < 16; ++p) {
      const float* src = Gpart + (((size_t)(p * 4 + b)) << 16) +
                         (size_t)(nt * 16 + rr) * 256 + c0;
#pragma unroll
      for (int e = 0; e < 4; ++e) s[e] += *(const f32x4*)(src + e * 4);
    }
    {
      float part = 0.f;
#pragma unroll
      for (int e = 0; e < 4; ++e) {
        const float4 vv = *(const float4*)(vb_g + c0 + e * 4);
        part += s[e][0] * vv.x + s[e][1] * vv.y + s[e][2] * vv.z + s[e][3] * vv.w;
      }
#pragma unroll
      for (int off = 8; off; off >>= 1) part += __shfl_down(part, off);
      if ((t & 15) == 0) t2_g[b * 256 + nt * 16 + rr] = part;
    }
    __bf16 h8[16], l8[16];
#pragma unroll
    for (int e = 0; e < 16; ++e) {
      const float x = s[e >> 2][e & 3];
      const __bf16 h = (__bf16)x;
      h8[e] = h; l8[e] = (__bf16)(x - (float)h);
    }
    *(bf16x8*)&Gsh[rr][c0] = *(bf16x8*)&h8[0];
    *(bf16x8*)&Gsh[rr][c0 + 8] = *(bf16x8*)&h8[8];
    *(bf16x8*)&Gsl[rr][c0] = *(bf16x8*)&l8[0];
    *(bf16x8*)&Gsl[rr][c0 + 8] = *(bf16x8*)&l8[8];
    __syncthreads();
    // ---- phase B: 4 independent W2 tiles per wave (mt = i*4 + wave) ----
    const int m = lane & 15, q = lane >> 4;
    f32x4 acc[4] = {};
#pragma unroll
    for (int ks = 0; ks < 8; ++ks) {
      const int k = ks * 32 + q * 8;
      const bf16x8 bh = *(const bf16x8*)&Gsh[m][k];
      const bf16x8 bl = *(const bf16x8*)&Gsl[m][k];
#pragma unroll
      for (int i = 0; i < 4; ++i) {
        const int mt = i * 4 + wave;
        const bf16x8 ah = *(const bf16x8*)(Wghi + (size_t)(mt * 16 + m) * 256 + k);
        const bf16x8 al = *(const bf16x8*)(Wglo + (size_t)(mt * 16 + m) * 256 + k);
        acc[i] = __builtin_amdgcn_mfma_f32_16x16x32_bf16(ah, bh, acc[i], 0, 0, 0);
        acc[i] = __builtin_amdgcn_mfma_f32_16x16x32_bf16(ah, bl, acc[i], 0, 0, 0);
        acc[i] = __builtin_amdgcn_mfma_f32_16x16x32_bf16(al, bh, acc[i], 0, 0, 0);
      }
    }
#pragma unroll
    for (int i = 0; i < 4; ++i) {
      const int mt = i * 4 + wave;
#pragma unroll
      for (int r = 0; r < 4; ++r) {
        const size_t off = ((size_t)b << 16) + (size_t)(mt * 16 + q * 4 + r) * 256 +
                           nt * 16 + m;
        const float v = acc[i][r];
        const __bf16 h = (__bf16)v;
        W2hi[off] = h;
        W2lo[off] = (__bf16)(v - (float)h);
      }
    }
  } else {
    // ---- aux: Wgs = Wg@s ; sPTv = PTt@s ; d2 = s.vb ----
    const int p = blk - 64;
    const int b = p >> 4, seg = p & 15;
    lds[t] = srow[b * 256 + t];
    __syncthreads();
    const float4 sv = *(const float4*)&lds[lane * 4];
    for (int i = wave; i < 16; i += 4) {
      const int o = seg * 16 + i;
      const float4 r = *(const float4*)(Wg + (size_t)o * 256 + lane * 4);
      float v = fmaf(r.x, sv.x, fmaf(r.y, sv.y, fmaf(r.z, sv.z, r.w * sv.w)));
      v = wave_reduce(v);
      if (lane == 0) Wgs[b * 256 + o] = v;
    }
    for (int i = wave; i < 16; i += 4) {
      const int c = seg * 16 + i;
      const bf16x4 ph = *(const bf16x4*)(PTthi + (size_t)c * 256 + lane * 4);
      const bf16x4 pl = *(const bf16x4*)(PTtlo + (size_t)c * 256 + lane * 4);
      const float svv[4] = {sv.x, sv.y, sv.z, sv.w};
      float v = 0.f;
#pragma unroll
      for (int e = 0; e < 4; ++e) v += ((float)ph[e] + (float)pl[e]) * svv[e];
      v = wave_reduce(v);
      if (lane == 0) sPTv[b * 256 + c] = v;
    }
    if (seg == 0 && wave == 0) {
      const float4 vbv = *(const float4*)(vb_g + lane * 4);
      float v = fmaf(vbv.x, sv.x, fmaf(vbv.y, sv.y, fmaf(vbv.z, sv.z, vbv.w * sv.w)));
      v = wave_reduce(v);
      if (lane == 0) dvec[1 + b] = v;
    }
  }
}

// ===== k3: W_out (blocks 0..63, 4 tiles/wave) + bias chain (64..79) =============
__global__ __launch_bounds__(256) void wout_mfma_kernel(
    const __bf16* __restrict__ W2hi, const __bf16* __restrict__ W2lo,
    const __bf16* __restrict__ PTthi, const __bf16* __restrict__ PTtlo,
    const float* __restrict__ Wgs, const float* __restrict__ sPT,
    const float* __restrict__ wgb, const float* __restrict__ vpt,
    const float* __restrict__ Wg, const float* __restrict__ t2_g,
    const float* __restrict__ dvec,
    const float* __restrict__ bn_gamma, const float* __restrict__ bn_beta,
    const float* __restrict__ bn_mean, const float* __restrict__ bn_var,
    __bf16* __restrict__ Whi, __bf16* __restrict__ Wlo,
    float* __restrict__ bias_out) {
  const int blk = blockIdx.x;
  const int t = threadIdx.x;
  const int wave = t >> 6, lane = t & 63;
  if (blk < 64) {
    const int batch = blk >> 4, nt = blk & 15;
    const int m = lane & 15, q = lane >> 4;
    const __bf16* bh_p = PTthi + (size_t)(nt * 16 + m) * 256;   // PTt row = PT column
    const __bf16* bl_p = PTtlo + (size_t)(nt * 16 + m) * 256;
    const __bf16* w2h = W2hi + (size_t)batch * 65536;
    const __bf16* w2l = W2lo + (size_t)batch * 65536;
    f32x4 acc[4] = {};
#pragma unroll
    for (int ks = 0; ks < 8; ++ks) {
      const int k = ks * 32 + q * 8;
      const bf16x8 bh = *(const bf16x8*)(bh_p + k);
      const bf16x8 bl = *(const bf16x8*)(bl_p + k);
#pragma unroll
      for (int i = 0; i < 4; ++i) {
        const int mt = i * 4 + wave;
        const bf16x8 ah = *(const bf16x8*)(w2h + (size_t)(mt * 16 + m) * 256 + k);
        const bf16x8 al = *(const bf16x8*)(w2l + (size_t)(mt * 16 + m) * 256 + k);
        acc[i] = __builtin_amdgcn_mfma_f32_16x16x32_bf16(ah, bh, acc[i], 0, 0, 0);
        acc[i] = __builtin_amdgcn_mfma_f32_16x16x32_bf16(ah, bl, acc[i], 0, 0, 0);
        acc[i] = __builtin_amdgcn_mfma_f32_16x16x32_bf16(al, bh, acc[i], 0, 0, 0);
      }
    }
    const float invN = 1.0f / 4096.0f;
    const int c = nt * 16 + m;
    const float vpt_c = vpt[c];
    const float sPT_c = sPT[batch * 256 + c];
#pragma unroll
    for (int i = 0; i < 4; ++i) {
      const int mt = i * 4 + wave;
#pragma unroll
      for (int r = 0; r < 4; ++r) {
        const int o = mt * 16 + q * 4 + r;
        const float sc = bn_gamma[o] * rsqrtf(bn_var[o] + BN_EPS);
        const float w = sc * ((acc[i][r] + Wgs[batch * 256 + o] * vpt_c + wgb[o] * sPT_c) * invN +
                              wgb[o] * vpt_c);
        const size_t off = (size_t)batch * 65536 + (size_t)o * 256 + c;
        const __bf16 h = (__bf16)w;
        Whi[off] = h;
        Wlo[off] = (__bf16)(w - (float)h);
      }
    }
  } else {
    // ---- bias chain: bias = sc*((Wg@t2 + Wgs*d1 + wgb*(d2+N*d1))/N - mean)+beta
    const int p = blk - 64;
    const int b = p >> 2, quarter = p & 3;
    __shared__ float t2s[256];
    t2s[t] = t2_g[b * 256 + t];
    __syncthreads();
    const float d1 = dvec[0], d2 = dvec[1 + b];
    const float invN = 1.0f / 4096.0f;
    const float4 tv = *(const float4*)&t2s[lane * 4];
    for (int it = 0; it < 16; ++it) {
      const int o = quarter * 64 + wave * 16 + it;
      const float4 r = *(const float4*)(Wg + (size_t)o * 256 + lane * 4);
      float v = fmaf(r.x, tv.x, fmaf(r.y, tv.y, fmaf(r.z, tv.z, r.w * tv.w)));
      v = wave_reduce(v);
      if (lane == 0) {
        const float bias_full = (v + Wgs[b * 256 + o] * d1 +
                                 wgb[o] * (d2 + 4096.0f * d1)) * invN;
        const float sc = bn_gamma[o] * rsqrtf(bn_var[o] + BN_EPS);
        bias_out[b * 256 + o] = sc * (bias_full - bn_mean[o]) + bn_beta[o];
      }
    }
  }
}

// ===== k4: out[b] = W_out[b] @ a[b] + bias (64x64 per block, 4 acc chains) ======
__global__ __launch_bounds__(256) void out_mfma_kernel(const __bf16* __restrict__ Whi,
                                                       const __bf16* __restrict__ Wlo,
                                                       const __bf16* __restrict__ at,
                                                       const float* __restrict__ bias_out,
                                                       float* __restrict__ out) {
  const int nt = blockIdx.x, mt = blockIdx.y, b = blockIdx.z;
  const int wave = threadIdx.x >> 6, lane = threadIdx.x & 63;
  const int m = lane & 15, q = lane >> 4;
  const int o = mt * 64 + wave * 16 + m;
  const __bf16* wh = Whi + (size_t)b * 65536 + (size_t)o * 256;
  const __bf16* wl = Wlo + (size_t)b * 65536 + (size_t)o * 256;
  const __bf16* atb = at + ((size_t)b * NSP + nt * 64) * CCH;
  f32x4 acc[4] = {};
#pragma unroll
  for (int ks = 0; ks < 8; ++ks) {
    const int k = ks * 32 + q * 8;
    const bf16x8 ah = *(const bf16x8*)(wh + k);
    const bf16x8 al = *(const bf16x8*)(wl + k);
#pragma unroll
    for (int t4 = 0; t4 < 4; ++t4) {
      const bf16x8 bh = *(const bf16x8*)(atb + (size_t)(t4 * 16 + m) * 256 + k);
      acc[t4] = __builtin_amdgcn_mfma_f32_16x16x32_bf16(ah, bh, acc[t4], 0, 0, 0);
      acc[t4] = __builtin_amdgcn_mfma_f32_16x16x32_bf16(al, bh, acc[t4], 0, 0, 0);
    }
  }
  float* ob = out + (size_t)b * CCH * NSP;
#pragma unroll
  for (int r = 0; r < 4; ++r) {
    const int orow = mt * 64 + wave * 16 + q * 4 + r;
    const float bo = bias_out[b * 256 + orow];
#pragma unroll
    for (int t4 = 0; t4 < 4; ++t4)
      ob[(size_t)orow * NSP + nt * 64 + t4 * 16 + m] = acc[t4][r] + bo;
  }
}

extern "C" void kernel_launch(void* const* d_in, const int* in_sizes, int n_in,
                              void* d_out, int out_size, void* d_ws, size_t ws_size,
                              hipStream_t stream) {
  (void)in_sizes; (void)n_in; (void)out_size; (void)ws_size;
  const float* a       = (const float*)d_in[0];
  const float* bI      = (const float*)d_in[1];
  const float* theta_w = (const float*)d_in[2];
  const float* theta_b = (const float*)d_in[3];
  const float* phi_w   = (const float*)d_in[4];
  const float* phi_b   = (const float*)d_in[5];
  const float* g_w     = (const float*)d_in[6];
  const float* g_b     = (const float*)d_in[7];
  const float* W_w     = (const float*)d_in[8];
  const float* bn_gamma= (const float*)d_in[9];
  const float* bn_beta = (const float*)d_in[10];
  const float* bn_mean = (const float*)d_in[11];
  const float* bn_var  = (const float*)d_in[12];
  float* out = (float*)d_out;
  float* ws  = (float*)d_ws;

  // fp32 region (float offsets)
  float* Gpart    = ws;                  // 4194304 (16 MB)
  float* srow     = ws + 4194304;        // 1024
  float* Wg       = ws + 4195328;        // 65536
  float* bias_out = ws + 4260864;        // 1024
  float* Wgs      = ws + 4261888;        // 1024
  float* sPTv     = ws + 4262912;        // 1024
  float* wgb      = ws + 4263936;        // 256
  float* vpt      = ws + 4264192;        // 256
  float* vb_g     = ws + 4264448;        // 256
  float* t2_g     = ws + 4264704;        // 1024
  float* dvec     = ws + 4265728;        // 8 (pad to 256)
  // bf16 region
  __bf16* at    = (__bf16*)(ws + 4265984);   // 8 MB
  __bf16* Wghi  = (__bf16*)(ws + 6363136);   // 128 KB each below
  __bf16* Wglo  = (__bf16*)(ws + 6395904);
  __bf16* PTthi = (__bf16*)(ws + 6428672);
  __bf16* PTtlo = (__bf16*)(ws + 6461440);
  __bf16* W2hi  = (__bf16*)(ws + 6494208);   // 512 KB each below
  __bf16* W2lo  = (__bf16*)(ws + 6625280);
  __bf16* Whi   = (__bf16*)(ws + 6756352);
  __bf16* Wlo   = (__bf16*)(ws + 6887424);
  __bf16* bhi   = (__bf16*)(ws + 7018496);   // 8 MB
  __bf16* blo   = (__bf16*)(ws + 9115648);   // 8 MB, end ~44.9 MB

  prep_kernel<<<dim3(2086), dim3(256), 0, stream>>>(bI, a, W_w, g_w, phi_w, theta_w,
                                                    phi_b, theta_b, g_b,
                                                    bhi, blo, srow, Wg, Wghi, Wglo,
                                                    PTthi, PTtlo, at,
                                                    vb_g, vpt, wgb, dvec);
  gram_kernel<<<dim3(1024), dim3(256), 0, stream>>>(bhi, blo, Gpart);
  redw2_kernel<<<dim3(128), dim3(256), 0, stream>>>(Gpart, vb_g, t2_g, srow, Wg,
                                                    Wghi, Wglo, PTthi, PTtlo,
                                                    W2hi, W2lo, Wgs, sPTv, dvec);
  wout_mfma_kernel<<<dim3(80), dim3(256), 0, stream>>>(W2hi, W2lo, PTthi, PTtlo,
                                                       Wgs, sPTv, wgb, vpt, Wg, t2_g,
                                                       dvec, bn_gamma, bn_beta, bn_mean,
                                                       bn_var, Whi, Wlo, bias_out);
  out_mfma_kernel<<<dim3(64, 4, 4), dim3(256), 0, stream>>>(Whi, Wlo, at, bias_out, out);
}

// Round 3
// 182.978 us; speedup vs baseline: 1.1125x; 1.0063x over previous
//
#include <hip/hip_runtime.h>
#include <hip/hip_bf16.h>

#define NSP 4096   // H*W
#define CCH 256    // C
#define CIN 128    // Ci
#define BN_EPS 1e-5f

typedef __bf16 bf16x8 __attribute__((ext_vector_type(8)));
typedef __bf16 bf16x4 __attribute__((ext_vector_type(4)));
typedef float f32x4 __attribute__((ext_vector_type(4)));
typedef unsigned short u16x8 __attribute__((ext_vector_type(8)));

typedef const __attribute__((address_space(1))) unsigned int gu32;
typedef __attribute__((address_space(3))) unsigned int lu32;

// ================= fp32 tile helpers (prep only) =================================

__device__ __forceinline__ float4 fetch_tr(const float* __restrict__ A, int lda, int m0,
                                           int k0, int tid) {
  const int r = tid >> 2, kq = (tid & 3) << 2;
  return *(const float4*)(A + (size_t)(m0 + r) * lda + k0 + kq);
}
__device__ __forceinline__ void stash_tr(float (*As)[68], float4 v, int tid) {
  const int r = tid >> 2, kq = (tid & 3) << 2;
  As[kq + 0][r] = v.x; As[kq + 1][r] = v.y; As[kq + 2][r] = v.z; As[kq + 3][r] = v.w;
}
__device__ __forceinline__ float4 fetch_dir(const float* __restrict__ B, int ldb, int k0,
                                            int n0, int tid) {
  const int kr = tid >> 4, nq = (tid & 15) << 2;
  return *(const float4*)(B + (size_t)(k0 + kr) * ldb + n0 + nq);
}
__device__ __forceinline__ void stash_dir(float (*Bs)[68], float4 v, int tid) {
  const int kr = tid >> 4, nq = (tid & 15) << 2;
  *(float4*)(&Bs[kr][nq]) = v;
}

__device__ __forceinline__ void mm16(const float (*As)[68], const float (*Bs)[68],
                                     float acc[4][4], int ty, int tx) {
#pragma unroll
  for (int kk = 0; kk < 16; ++kk) {
    const float4 av = *(const float4*)(&As[kk][ty << 2]);
    const float4 bv = *(const float4*)(&Bs[kk][tx << 2]);
    const float ar[4] = {av.x, av.y, av.z, av.w};
    const float br[4] = {bv.x, bv.y, bv.z, bv.w};
#pragma unroll
    for (int i = 0; i < 4; ++i)
#pragma unroll
      for (int j = 0; j < 4; ++j) acc[i][j] += ar[i] * br[j];
  }
}

__device__ __forceinline__ float wave_reduce(float v) {
#pragma unroll
  for (int off = 32; off; off >>= 1) v += __shfl_down(v, off);
  return v;  // valid in lane 0
}

// ===== k0: all independent prep in one dispatch =================================
// cast_b+srow(0..1023) + cast_a(1024..2047) + prep(2048..2079) + vb/d1(2080)
// + vpt(2081) + wgb(2082..2085)
__global__ __launch_bounds__(256) void prep_kernel(
    const float* __restrict__ bin, const float* __restrict__ a,
    const float* __restrict__ W_w, const float* __restrict__ g_w,
    const float* __restrict__ phi_w, const float* __restrict__ theta_w,
    const float* __restrict__ phi_b, const float* __restrict__ theta_b,
    const float* __restrict__ g_b,
    __bf16* __restrict__ bhi, __bf16* __restrict__ blo,
    float* __restrict__ srow,
    float* __restrict__ Wg, __bf16* __restrict__ Wghi, __bf16* __restrict__ Wglo,
    __bf16* __restrict__ PTthi, __bf16* __restrict__ PTtlo,
    __bf16* __restrict__ at,
    float* __restrict__ vb_g, float* __restrict__ vpt, float* __restrict__ wgb,
    float* __restrict__ dvec) {
  __shared__ float smem[64 * 68];
  const int idx = blockIdx.x;
  const int t = threadIdx.x;
  const int wave = t >> 6, lane = t & 63;
  if (idx < 1024) {
    // ---- cast b -> bf16 hi/lo (truncation, identical to old f8_hilo) + exact srow
    const int row = idx;  // global row over 4*256
    const float* src = bin + (size_t)row * NSP + t * 16;
    float sum = 0.f;
    unsigned short h16[16], l16[16];
#pragma unroll
    for (int i = 0; i < 4; ++i) {
      const float4 v = *(const float4*)(src + i * 4);
      const float vv[4] = {v.x, v.y, v.z, v.w};
      sum += v.x + v.y + v.z + v.w;
#pragma unroll
      for (int e = 0; e < 4; ++e) {
        const unsigned u = __float_as_uint(vv[e]);
        h16[i * 4 + e] = (unsigned short)(u >> 16);
        const float hf = __uint_as_float(u & 0xffff0000u);
        l16[i * 4 + e] = (unsigned short)(__float_as_uint(vv[e] - hf) >> 16);
      }
    }
    unsigned short* dh = (unsigned short*)bhi + (size_t)row * NSP + t * 16;
    unsigned short* dl = (unsigned short*)blo + (size_t)row * NSP + t * 16;
    *(u16x8*)dh = *(u16x8*)&h16[0];
    *(u16x8*)(dh + 8) = *(u16x8*)&h16[8];
    *(u16x8*)dl = *(u16x8*)&l16[0];
    *(u16x8*)(dl + 8) = *(u16x8*)&l16[8];
#pragma unroll
    for (int off = 32; off; off >>= 1) sum += __shfl_down(sum, off);
    if (lane == 0) smem[wave] = sum;
    __syncthreads();
    if (t == 0) srow[row] = smem[0] + smem[1] + smem[2] + smem[3];
  } else if (idx < 2048) {
    // ---- cast a -> bf16 transposed: at[b][n][c] ----
    const int p = idx - 1024;
    const int n0 = (p & 63) * 64, c0 = ((p >> 6) & 3) * 64, b = p >> 8;
    float (*tile)[68] = (float(*)[68])smem;
    const int cr = t >> 4, nq = (t & 15) << 2;
    const float* src = a + ((size_t)(b * CCH + c0)) * NSP + n0;
#pragma unroll
    for (int s = 0; s < 4; ++s) {
      const float4 v = *(const float4*)(src + (size_t)(cr + s * 16) * NSP + nq);
      *(float4*)&tile[cr + s * 16][nq] = v;
    }
    __syncthreads();
    const int n = t >> 2, cq = (t & 3) << 4;
    __bf16 outv[16];
#pragma unroll
    for (int i = 0; i < 16; ++i) outv[i] = (__bf16)tile[cq + i][n];
    __bf16* dst = at + ((size_t)(b * NSP + n0 + n)) * CCH + c0 + cq;
    *(bf16x8*)dst = *(bf16x8*)&outv[0];
    *(bf16x8*)(dst + 8) = *(bf16x8*)&outv[8];
  } else if (idx < 2080) {
    // ---- prep: Wg = W_w @ g_w (z=0) ; PTt = theta_w^T @ phi_w (z=1) ----
    const int p = idx - 2048;
    const int zsel = p >> 4, rem = p & 15;
    const int m0 = (rem >> 2) * 64, n0 = (rem & 3) * 64;
    float (*As)[68] = (float(*)[68])smem;
    float (*Bs)[68] = (float(*)[68])(smem + 16 * 68);
    const int ty = t >> 4, tx = t & 15;
    float acc[4][4] = {};
    if (zsel == 0) {
      float4 ar = fetch_tr(W_w, CIN, m0, 0, t);
      float4 br = fetch_dir(g_w, CCH, 0, n0, t);
      for (int kt = 0; kt < 8; ++kt) {
        stash_tr(As, ar, t); stash_dir(Bs, br, t);
        __syncthreads();
        if (kt < 7) { ar = fetch_tr(W_w, CIN, m0, (kt + 1) * 16, t);
                      br = fetch_dir(g_w, CCH, (kt + 1) * 16, n0, t); }
        mm16(As, Bs, acc, ty, tx);
        __syncthreads();
      }
#pragma unroll
      for (int i = 0; i < 4; ++i) {
        const size_t off = (size_t)(m0 + (ty << 2) + i) * 256 + n0 + (tx << 2);
        *(float4*)(Wg + off) = make_float4(acc[i][0], acc[i][1], acc[i][2], acc[i][3]);
        __bf16 h4[4], l4[4];
#pragma unroll
        for (int j = 0; j < 4; ++j) {
          const __bf16 h = (__bf16)acc[i][j];
          h4[j] = h; l4[j] = (__bf16)(acc[i][j] - (float)h);
        }
        *(bf16x4*)(Wghi + off) = *(bf16x4*)h4;
        *(bf16x4*)(Wglo + off) = *(bf16x4*)l4;
      }
    } else {
      float4 ar = fetch_dir(theta_w, CCH, 0, m0, t);   // swapped: computes PT^T
      float4 br = fetch_dir(phi_w, CCH, 0, n0, t);
      for (int kt = 0; kt < 8; ++kt) {
        stash_dir(As, ar, t); stash_dir(Bs, br, t);
        __syncthreads();
        if (kt < 7) { ar = fetch_dir(theta_w, CCH, (kt + 1) * 16, m0, t);
                      br = fetch_dir(phi_w, CCH, (kt + 1) * 16, n0, t); }
        mm16(As, Bs, acc, ty, tx);
        __syncthreads();
      }
#pragma unroll
      for (int i = 0; i < 4; ++i) {
        const size_t off = (size_t)(m0 + (ty << 2) + i) * 256 + n0 + (tx << 2);
        __bf16 h4[4], l4[4];
#pragma unroll
        for (int j = 0; j < 4; ++j) {
          const __bf16 h = (__bf16)acc[i][j];
          h4[j] = h; l4[j] = (__bf16)(acc[i][j] - (float)h);
        }
        *(bf16x4*)(PTthi + off) = *(bf16x4*)h4;
        *(bf16x4*)(PTtlo + off) = *(bf16x4*)l4;
      }
    }
  } else if (idx == 2080) {
    // ---- vb[c] = phi_w^T @ theta_b ; d1 = phi_b . theta_b ----
    float* tb_s = smem;
    float* pb_s = smem + 128;
    if (t < 128) { tb_s[t] = theta_b[t]; pb_s[t] = phi_b[t]; }
    __syncthreads();
    float acc = 0.f;
#pragma unroll 8
    for (int i = 0; i < 128; ++i) acc += phi_w[(size_t)i * 256 + t] * tb_s[i];
    vb_g[t] = acc;
    if (t < 64) {
      float pv = pb_s[t] * tb_s[t] + pb_s[t + 64] * tb_s[t + 64];
      pv = wave_reduce(pv);
      if (t == 0) dvec[0] = pv;
    }
  } else if (idx == 2081) {
    // ---- vpt[c] = phi_b^T @ theta_w ----
    float* pb_s = smem;
    if (t < 128) pb_s[t] = phi_b[t];
    __syncthreads();
    float acc = 0.f;
#pragma unroll 8
    for (int i = 0; i < 128; ++i) acc += pb_s[i] * theta_w[(size_t)i * 256 + t];
    vpt[t] = acc;
  } else {
    // ---- wgb[o] = W_w[o] . g_b : 4 blocks x 64 outputs ----
    const int p = idx - 2082;
    float* gb_s = smem;
    if (t < 128) gb_s[t] = g_b[t];
    __syncthreads();
    const float2 gv = *(const float2*)&gb_s[lane * 2];
    for (int i = 0; i < 16; ++i) {
      const int o = p * 64 + wave * 16 + i;
      const float2 r = *(const float2*)(W_w + (size_t)o * 128 + lane * 2);
      float v = fmaf(r.x, gv.x, r.y * gv.y);
      v = wave_reduce(v);
      if (lane == 0) wgb[o] = v;
    }
  }
}

// ===== k1: gram partials — LDS-staged bf16 MFMA GEMM (global_load_lds, dbuf) ====
// kc-split = 8: per block (jt,it,kc,batch): G_tile[64x64] over k=512 (16 ks steps).
// LDS tiles hold a 32-k slab as 8 chunks/row of 16B: chunk ch = (h*4 + j) ^ (r&7)
// (h: 0=hi 1=lo, j: k-quad). Swizzle applied on the per-lane GLOBAL source address
// (LDS dest of global_load_lds is linear wave-uniform-base + lane*16), and undone
// identically on the ds_read side -> banks balanced, numerics bit-identical.
__global__ __launch_bounds__(256) void gram_kernel(
    const __bf16* __restrict__ bhi, const __bf16* __restrict__ blo,
    float* __restrict__ Gpart) {
  __shared__ __bf16 At[2][64][64];
  __shared__ __bf16 Bt[2][64][64];
  const int idx = blockIdx.x;
  const int t = threadIdx.x;
  const int wave = t >> 6, lane = t & 63;
  const int jt = idx & 3, it = (idx >> 2) & 3;
  const int z = idx >> 4, batch = z >> 3, kc = z & 7;
  const int m = lane & 15, q = lane >> 4;
  const size_t rowbase = (size_t)batch * CCH;
  const int colbase = kc * 512;
  // staging lane geometry (constant per lane): r_in_seg, chunk, unswizzled (h,j)
  const int rseg = lane >> 3, ch = lane & 7;
  const int u = ch ^ rseg;          // r&7 == rseg since segments are 8-row aligned
  const int h = u >> 2, j = u & 3;
  const __bf16* gsrc = h ? blo : bhi;

  auto stage = [&](int ph, int ks) {
#pragma unroll
    for (int c = 0; c < 4; ++c) {
      const int s = wave * 4 + c;       // 0..15: 0-7 A-tile KBs, 8-15 B-tile KBs
      const int isB = s >> 3;
      const int kb = s & 7;
      const int grow = (isB ? jt : it) * 64 + kb * 8 + rseg;
      const __bf16* gp = gsrc + (rowbase + (size_t)grow) * NSP +
                         colbase + ks * 32 + j * 8;
      const __bf16* lp = isB ? &Bt[ph][kb * 8][0] : &At[ph][kb * 8][0];
      __builtin_amdgcn_global_load_lds((gu32*)(const void*)gp,
                                       (lu32*)(void*)lp, 16, 0, 0);
    }
  };

  f32x4 acc[4] = {};
  const int chA = q ^ (m & 7);        // hi chunk for this lane's rows (r&7 == m&7)
  stage(0, 0);
  int ph = 0;
  for (int ks = 0; ks < 16; ++ks) {
    __syncthreads();                  // stage(ks) visible (vmcnt drained at barrier)
    if (ks < 15) stage(ph ^ 1, ks + 1);
    const bf16x8 ah = *(const bf16x8*)&At[ph][wave * 16 + m][chA * 8];
    const bf16x8 al = *(const bf16x8*)&At[ph][wave * 16 + m][(chA ^ 4) * 8];
#pragma unroll
    for (int t4 = 0; t4 < 4; ++t4) {
      const bf16x8 bh = *(const bf16x8*)&Bt[ph][t4 * 16 + m][chA * 8];
      const bf16x8 bl = *(const bf16x8*)&Bt[ph][t4 * 16 + m][(chA ^ 4) * 8];
      acc[t4] = __builtin_amdgcn_mfma_f32_16x16x32_bf16(ah, bh, acc[t4], 0, 0, 0);
      acc[t4] = __builtin_amdgcn_mfma_f32_16x16x32_bf16(ah, bl, acc[t4], 0, 0, 0);
      acc[t4] = __builtin_amdgcn_mfma_f32_16x16x32_bf16(al, bh, acc[t4], 0, 0, 0);
    }
    ph ^= 1;
  }
  float* Gp = Gpart + ((size_t)(kc * 4 + batch)) * 65536;
#pragma unroll
  for (int t4 = 0; t4 < 4; ++t4)
#pragma unroll
    for (int r = 0; r < 4; ++r)
      Gp[(size_t)(it * 64 + wave * 16 + q * 4 + r) * 256 + jt * 64 + t4 * 16 + m] =
          acc[t4][r];
}

// ===== k2: fused reduce+W2, 1x Gpart read (blocks 0..63) + aux (64..127) ========
__global__ __launch_bounds__(256) void redw2_kernel(
    const float* __restrict__ Gpart, const float* __restrict__ vb_g,
    float* __restrict__ t2_g, const float* __restrict__ srow,
    const float* __restrict__ Wg,
    const __bf16* __restrict__ Wghi, const __bf16* __restrict__ Wglo,
    const __bf16* __restrict__ PTthi, const __bf16* __restrict__ PTtlo,
    __bf16* __restrict__ W2hi, __bf16* __restrict__ W2lo,
    float* __restrict__ Wgs, float* __restrict__ sPTv, float* __restrict__ dvec) {
  const int blk = blockIdx.x;
  const int t = threadIdx.x;
  const int wave = t >> 6, lane = t & 63;
  __shared__ __bf16 Gsh[16][264], Gsl[16][264];   // +8 pad: 2-way banks only
  __shared__ float lds[256];
  if (blk < 64) {
    const int b = blk >> 4, nt = blk & 15;
    // ---- phase A: reduce 16 rows x 256 cols over 8 partials (read once) ----
    const int rr = t >> 4;
    const int c0 = (t & 15) * 16;
    f32x4 s[4] = {};
#pragma unroll
    for (int p = 0; p < 8; ++p) {
      const float* src = Gpart + (((size_t)(p * 4 + b)) << 16) +
                         (size_t)(nt * 16 + rr) * 256 + c0;
#pragma unroll
      for (int e = 0; e < 4; ++e) s[e] += *(const f32x4*)(src + e * 4);
    }
    {
      float part = 0.f;
#pragma unroll
      for (int e = 0; e < 4; ++e) {
        const float4 vv = *(const float4*)(vb_g + c0 + e * 4);
        part += s[e][0] * vv.x + s[e][1] * vv.y + s[e][2] * vv.z + s[e][3] * vv.w;
      }
#pragma unroll
      for (int off = 8; off; off >>= 1) part += __shfl_down(part, off);
      if ((t & 15) == 0) t2_g[b * 256 + nt * 16 + rr] = part;
    }
    __bf16 h8[16], l8[16];
#pragma unroll
    for (int e = 0; e < 16; ++e) {
      const float x = s[e >> 2][e & 3];
      const __bf16 h = (__bf16)x;
      h8[e] = h; l8[e] = (__bf16)(x - (float)h);
    }
    *(bf16x8*)&Gsh[rr][c0] = *(bf16x8*)&h8[0];
    *(bf16x8*)&Gsh[rr][c0 + 8] = *(bf16x8*)&h8[8];
    *(bf16x8*)&Gsl[rr][c0] = *(bf16x8*)&l8[0];
    *(bf16x8*)&Gsl[rr][c0 + 8] = *(bf16x8*)&l8[8];
    __syncthreads();
    // ---- phase B: 4 independent W2 tiles per wave (mt = i*4 + wave) ----
    const int m = lane & 15, q = lane >> 4;
    f32x4 acc[4] = {};
#pragma unroll
    for (int ks = 0; ks < 8; ++ks) {
      const int k = ks * 32 + q * 8;
      const bf16x8 bh = *(const bf16x8*)&Gsh[m][k];
      const bf16x8 bl = *(const bf16x8*)&Gsl[m][k];
#pragma unroll
      for (int i = 0; i < 4; ++i) {
        const int mt = i * 4 + wave;
        const bf16x8 ah = *(const bf16x8*)(Wghi + (size_t)(mt * 16 + m) * 256 + k);
        const bf16x8 al = *(const bf16x8*)(Wglo + (size_t)(mt * 16 + m) * 256 + k);
        acc[i] = __builtin_amdgcn_mfma_f32_16x16x32_bf16(ah, bh, acc[i], 0, 0, 0);
        acc[i] = __builtin_amdgcn_mfma_f32_16x16x32_bf16(ah, bl, acc[i], 0, 0, 0);
        acc[i] = __builtin_amdgcn_mfma_f32_16x16x32_bf16(al, bh, acc[i], 0, 0, 0);
      }
    }
#pragma unroll
    for (int i = 0; i < 4; ++i) {
      const int mt = i * 4 + wave;
#pragma unroll
      for (int r = 0; r < 4; ++r) {
        const size_t off = ((size_t)b << 16) + (size_t)(mt * 16 + q * 4 + r) * 256 +
                           nt * 16 + m;
        const float v = acc[i][r];
        const __bf16 h = (__bf16)v;
        W2hi[off] = h;
        W2lo[off] = (__bf16)(v - (float)h);
      }
    }
  } else {
    // ---- aux: Wgs = Wg@s ; sPTv = PTt@s ; d2 = s.vb ----
    const int p = blk - 64;
    const int b = p >> 4, seg = p & 15;
    lds[t] = srow[b * 256 + t];
    __syncthreads();
    const float4 sv = *(const float4*)&lds[lane * 4];
    for (int i = wave; i < 16; i += 4) {
      const int o = seg * 16 + i;
      const float4 r = *(const float4*)(Wg + (size_t)o * 256 + lane * 4);
      float v = fmaf(r.x, sv.x, fmaf(r.y, sv.y, fmaf(r.z, sv.z, r.w * sv.w)));
      v = wave_reduce(v);
      if (lane == 0) Wgs[b * 256 + o] = v;
    }
    for (int i = wave; i < 16; i += 4) {
      const int c = seg * 16 + i;
      const bf16x4 ph = *(const bf16x4*)(PTthi + (size_t)c * 256 + lane * 4);
      const bf16x4 pl = *(const bf16x4*)(PTtlo + (size_t)c * 256 + lane * 4);
      const float svv[4] = {sv.x, sv.y, sv.z, sv.w};
      float v = 0.f;
#pragma unroll
      for (int e = 0; e < 4; ++e) v += ((float)ph[e] + (float)pl[e]) * svv[e];
      v = wave_reduce(v);
      if (lane == 0) sPTv[b * 256 + c] = v;
    }
    if (seg == 0 && wave == 0) {
      const float4 vbv = *(const float4*)(vb_g + lane * 4);
      float v = fmaf(vbv.x, sv.x, fmaf(vbv.y, sv.y, fmaf(vbv.z, sv.z, vbv.w * sv.w)));
      v = wave_reduce(v);
      if (lane == 0) dvec[1 + b] = v;
    }
  }
}

// ===== k3: W_out (blocks 0..63, 4 tiles/wave) + bias chain (64..79) =============
__global__ __launch_bounds__(256) void wout_mfma_kernel(
    const __bf16* __restrict__ W2hi, const __bf16* __restrict__ W2lo,
    const __bf16* __restrict__ PTthi, const __bf16* __restrict__ PTtlo,
    const float* __restrict__ Wgs, const float* __restrict__ sPT,
    const float* __restrict__ wgb, const float* __restrict__ vpt,
    const float* __restrict__ Wg, const float* __restrict__ t2_g,
    const float* __restrict__ dvec,
    const float* __restrict__ bn_gamma, const float* __restrict__ bn_beta,
    const float* __restrict__ bn_mean, const float* __restrict__ bn_var,
    __bf16* __restrict__ Whi, __bf16* __restrict__ Wlo,
    float* __restrict__ bias_out) {
  const int blk = blockIdx.x;
  const int t = threadIdx.x;
  const int wave = t >> 6, lane = t & 63;
  if (blk < 64) {
    const int batch = blk >> 4, nt = blk & 15;
    const int m = lane & 15, q = lane >> 4;
    const __bf16* bh_p = PTthi + (size_t)(nt * 16 + m) * 256;   // PTt row = PT column
    const __bf16* bl_p = PTtlo + (size_t)(nt * 16 + m) * 256;
    const __bf16* w2h = W2hi + (size_t)batch * 65536;
    const __bf16* w2l = W2lo + (size_t)batch * 65536;
    f32x4 acc[4] = {};
#pragma unroll
    for (int ks = 0; ks < 8; ++ks) {
      const int k = ks * 32 + q * 8;
      const bf16x8 bh = *(const bf16x8*)(bh_p + k);
      const bf16x8 bl = *(const bf16x8*)(bl_p + k);
#pragma unroll
      for (int i = 0; i < 4; ++i) {
        const int mt = i * 4 + wave;
        const bf16x8 ah = *(const bf16x8*)(w2h + (size_t)(mt * 16 + m) * 256 + k);
        const bf16x8 al = *(const bf16x8*)(w2l + (size_t)(mt * 16 + m) * 256 + k);
        acc[i] = __builtin_amdgcn_mfma_f32_16x16x32_bf16(ah, bh, acc[i], 0, 0, 0);
        acc[i] = __builtin_amdgcn_mfma_f32_16x16x32_bf16(ah, bl, acc[i], 0, 0, 0);
        acc[i] = __builtin_amdgcn_mfma_f32_16x16x32_bf16(al, bh, acc[i], 0, 0, 0);
      }
    }
    const float invN = 1.0f / 4096.0f;
    const int c = nt * 16 + m;
    const float vpt_c = vpt[c];
    const float sPT_c = sPT[batch * 256 + c];
#pragma unroll
    for (int i = 0; i < 4; ++i) {
      const int mt = i * 4 + wave;
#pragma unroll
      for (int r = 0; r < 4; ++r) {
        const int o = mt * 16 + q * 4 + r;
        const float sc = bn_gamma[o] * rsqrtf(bn_var[o] + BN_EPS);
        const float w = sc * ((acc[i][r] + Wgs[batch * 256 + o] * vpt_c + wgb[o] * sPT_c) * invN +
                              wgb[o] * vpt_c);
        const size_t off = (size_t)batch * 65536 + (size_t)o * 256 + c;
        const __bf16 h = (__bf16)w;
        Whi[off] = h;
        Wlo[off] = (__bf16)(w - (float)h);
      }
    }
  } else {
    // ---- bias chain: bias = sc*((Wg@t2 + Wgs*d1 + wgb*(d2+N*d1))/N - mean)+beta
    const int p = blk - 64;
    const int b = p >> 2, quarter = p & 3;
    __shared__ float t2s[256];
    t2s[t] = t2_g[b * 256 + t];
    __syncthreads();
    const float d1 = dvec[0], d2 = dvec[1 + b];
    const float invN = 1.0f / 4096.0f;
    const float4 tv = *(const float4*)&t2s[lane * 4];
    for (int it = 0; it < 16; ++it) {
      const int o = quarter * 64 + wave * 16 + it;
      const float4 r = *(const float4*)(Wg + (size_t)o * 256 + lane * 4);
      float v = fmaf(r.x, tv.x, fmaf(r.y, tv.y, fmaf(r.z, tv.z, r.w * tv.w)));
      v = wave_reduce(v);
      if (lane == 0) {
        const float bias_full = (v + Wgs[b * 256 + o] * d1 +
                                 wgb[o] * (d2 + 4096.0f * d1)) * invN;
        const float sc = bn_gamma[o] * rsqrtf(bn_var[o] + BN_EPS);
        bias_out[b * 256 + o] = sc * (bias_full - bn_mean[o]) + bn_beta[o];
      }
    }
  }
}

// ===== k4: out[b] = W_out[b] @ a[b] + bias — register-resident W ================
// Block (ng,mt,b): wave's W rows (hi+lo, 8 ks x 16B each) loaded ONCE into 64
// VGPRs, then 4 n-subtiles of pure {at-load -> MFMA} with no barriers: the
// compiler pipelines subtile i+1 loads under subtile i MFMAs. MFMA order per
// output identical to previous version -> bit-identical numerics.
__global__ __launch_bounds__(256, 2) void out_mfma_kernel(const __bf16* __restrict__ Whi,
                                                          const __bf16* __restrict__ Wlo,
                                                          const __bf16* __restrict__ at,
                                                          const float* __restrict__ bias_out,
                                                          float* __restrict__ out) {
  const int ng = blockIdx.x, mt = blockIdx.y, b = blockIdx.z;
  const int wave = threadIdx.x >> 6, lane = threadIdx.x & 63;
  const int m = lane & 15, q = lane >> 4;
  const int o = mt * 64 + wave * 16 + m;
  const __bf16* wh = Whi + (size_t)b * 65536 + (size_t)o * 256;
  const __bf16* wl = Wlo + (size_t)b * 65536 + (size_t)o * 256;
  bf16x8 ah[8], al[8];
#pragma unroll
  for (int ks = 0; ks < 8; ++ks) {
    ah[ks] = *(const bf16x8*)(wh + ks * 32 + q * 8);
    al[ks] = *(const bf16x8*)(wl + ks * 32 + q * 8);
  }
  float bo[4];
#pragma unroll
  for (int r = 0; r < 4; ++r)
    bo[r] = bias_out[b * 256 + mt * 64 + wave * 16 + q * 4 + r];
  float* ob = out + (size_t)b * CCH * NSP;
#pragma unroll
  for (int nt4 = 0; nt4 < 4; ++nt4) {
    const __bf16* atb = at + ((size_t)b * NSP + ng * 256 + nt4 * 64) * CCH;
    f32x4 acc[4] = {};
#pragma unroll
    for (int ks = 0; ks < 8; ++ks) {
      const int k = ks * 32 + q * 8;
#pragma unroll
      for (int t4 = 0; t4 < 4; ++t4) {
        const bf16x8 bh = *(const bf16x8*)(atb + (size_t)(t4 * 16 + m) * 256 + k);
        acc[t4] = __builtin_amdgcn_mfma_f32_16x16x32_bf16(ah[ks], bh, acc[t4], 0, 0, 0);
        acc[t4] = __builtin_amdgcn_mfma_f32_16x16x32_bf16(al[ks], bh, acc[t4], 0, 0, 0);
      }
    }
#pragma unroll
    for (int r = 0; r < 4; ++r) {
      const int orow = mt * 64 + wave * 16 + q * 4 + r;
#pragma unroll
      for (int t4 = 0; t4 < 4; ++t4)
        ob[(size_t)orow * NSP + ng * 256 + nt4 * 64 + t4 * 16 + m] = acc[t4][r] + bo[r];
    }
  }
}

extern "C" void kernel_launch(void* const* d_in, const int* in_sizes, int n_in,
                              void* d_out, int out_size, void* d_ws, size_t ws_size,
                              hipStream_t stream) {
  (void)in_sizes; (void)n_in; (void)out_size; (void)ws_size;
  const float* a       = (const float*)d_in[0];
  const float* bI      = (const float*)d_in[1];
  const float* theta_w = (const float*)d_in[2];
  const float* theta_b = (const float*)d_in[3];
  const float* phi_w   = (const float*)d_in[4];
  const float* phi_b   = (const float*)d_in[5];
  const float* g_w     = (const float*)d_in[6];
  const float* g_b     = (const float*)d_in[7];
  const float* W_w     = (const float*)d_in[8];
  const float* bn_gamma= (const float*)d_in[9];
  const float* bn_beta = (const float*)d_in[10];
  const float* bn_mean = (const float*)d_in[11];
  const float* bn_var  = (const float*)d_in[12];
  float* out = (float*)d_out;
  float* ws  = (float*)d_ws;

  // fp32 region (float offsets)
  float* Gpart    = ws;                  // now 8 MB used (kc-split 8)
  float* srow     = ws + 4194304;        // 1024
  float* Wg       = ws + 4195328;        // 65536
  float* bias_out = ws + 4260864;        // 1024
  float* Wgs      = ws + 4261888;        // 1024
  float* sPTv     = ws + 4262912;        // 1024
  float* wgb      = ws + 4263936;        // 256
  float* vpt      = ws + 4264192;        // 256
  float* vb_g     = ws + 4264448;        // 256
  float* t2_g     = ws + 4264704;        // 1024
  float* dvec     = ws + 4265728;        // 8 (pad to 256)
  // bf16 region
  __bf16* at    = (__bf16*)(ws + 4265984);   // 8 MB
  __bf16* Wghi  = (__bf16*)(ws + 6363136);   // 128 KB each below
  __bf16* Wglo  = (__bf16*)(ws + 6395904);
  __bf16* PTthi = (__bf16*)(ws + 6428672);
  __bf16* PTtlo = (__bf16*)(ws + 6461440);
  __bf16* W2hi  = (__bf16*)(ws + 6494208);   // 512 KB each below
  __bf16* W2lo  = (__bf16*)(ws + 6625280);
  __bf16* Whi   = (__bf16*)(ws + 6756352);
  __bf16* Wlo   = (__bf16*)(ws + 6887424);
  __bf16* bhi   = (__bf16*)(ws + 7018496);   // 8 MB
  __bf16* blo   = (__bf16*)(ws + 9115648);   // 8 MB, end ~44.9 MB

  prep_kernel<<<dim3(2086), dim3(256), 0, stream>>>(bI, a, W_w, g_w, phi_w, theta_w,
                                                    phi_b, theta_b, g_b,
                                                    bhi, blo, srow, Wg, Wghi, Wglo,
                                                    PTthi, PTtlo, at,
                                                    vb_g, vpt, wgb, dvec);
  gram_kernel<<<dim3(512), dim3(256), 0, stream>>>(bhi, blo, Gpart);
  redw2_kernel<<<dim3(128), dim3(256), 0, stream>>>(Gpart, vb_g, t2_g, srow, Wg,
                                                    Wghi, Wglo, PTthi, PTtlo,
                                                    W2hi, W2lo, Wgs, sPTv, dvec);
  wout_mfma_kernel<<<dim3(80), dim3(256), 0, stream>>>(W2hi, W2lo, PTthi, PTtlo,
                                                       Wgs, sPTv, wgb, vpt, Wg, t2_g,
                                                       dvec, bn_gamma, bn_beta, bn_mean,
                                                       bn_var, Whi, Wlo, bias_out);
  out_mfma_kernel<<<dim3(16, 4, 4), dim3(256), 0, stream>>>(Whi, Wlo, at, bias_out, out);
}

// Round 4
// 175.152 us; speedup vs baseline: 1.1622x; 1.0447x over previous
//
#include <hip/hip_runtime.h>
#include <hip/hip_bf16.h>

#define NSP 4096   // H*W
#define CCH 256    // C
#define CIN 128    // Ci
#define BN_EPS 1e-5f

typedef __bf16 bf16x8 __attribute__((ext_vector_type(8)));
typedef __bf16 bf16x4 __attribute__((ext_vector_type(4)));
typedef float f32x4 __attribute__((ext_vector_type(4)));
typedef unsigned short u16x8 __attribute__((ext_vector_type(8)));

typedef const __attribute__((address_space(1))) unsigned int gu32;
typedef __attribute__((address_space(3))) unsigned int lu32;

// ================= fp32 tile helpers (prep only) =================================

__device__ __forceinline__ float4 fetch_tr(const float* __restrict__ A, int lda, int m0,
                                           int k0, int tid) {
  const int r = tid >> 2, kq = (tid & 3) << 2;
  return *(const float4*)(A + (size_t)(m0 + r) * lda + k0 + kq);
}
__device__ __forceinline__ void stash_tr(float (*As)[68], float4 v, int tid) {
  const int r = tid >> 2, kq = (tid & 3) << 2;
  As[kq + 0][r] = v.x; As[kq + 1][r] = v.y; As[kq + 2][r] = v.z; As[kq + 3][r] = v.w;
}
__device__ __forceinline__ float4 fetch_dir(const float* __restrict__ B, int ldb, int k0,
                                            int n0, int tid) {
  const int kr = tid >> 4, nq = (tid & 15) << 2;
  return *(const float4*)(B + (size_t)(k0 + kr) * ldb + n0 + nq);
}
__device__ __forceinline__ void stash_dir(float (*Bs)[68], float4 v, int tid) {
  const int kr = tid >> 4, nq = (tid & 15) << 2;
  *(float4*)(&Bs[kr][nq]) = v;
}

__device__ __forceinline__ void mm16(const float (*As)[68], const float (*Bs)[68],
                                     float acc[4][4], int ty, int tx) {
#pragma unroll
  for (int kk = 0; kk < 16; ++kk) {
    const float4 av = *(const float4*)(&As[kk][ty << 2]);
    const float4 bv = *(const float4*)(&Bs[kk][tx << 2]);
    const float ar[4] = {av.x, av.y, av.z, av.w};
    const float br[4] = {bv.x, bv.y, bv.z, bv.w};
#pragma unroll
    for (int i = 0; i < 4; ++i)
#pragma unroll
      for (int j = 0; j < 4; ++j) acc[i][j] += ar[i] * br[j];
  }
}

__device__ __forceinline__ float wave_reduce(float v) {
#pragma unroll
  for (int off = 32; off; off >>= 1) v += __shfl_down(v, off);
  return v;  // valid in lane 0
}

// ===== k0: all independent prep in one dispatch =================================
// cast_b+srow(0..1023) + cast_a(1024..2047) + prep(2048..2079) + vb/d1(2080)
// + vpt(2081) + wgb(2082..2085)
__global__ __launch_bounds__(256) void prep_kernel(
    const float* __restrict__ bin, const float* __restrict__ a,
    const float* __restrict__ W_w, const float* __restrict__ g_w,
    const float* __restrict__ phi_w, const float* __restrict__ theta_w,
    const float* __restrict__ phi_b, const float* __restrict__ theta_b,
    const float* __restrict__ g_b,
    __bf16* __restrict__ bhi, __bf16* __restrict__ blo,
    float* __restrict__ srow,
    float* __restrict__ Wg, __bf16* __restrict__ Wghi, __bf16* __restrict__ Wglo,
    __bf16* __restrict__ PTthi, __bf16* __restrict__ PTtlo,
    __bf16* __restrict__ at,
    float* __restrict__ vb_g, float* __restrict__ vpt, float* __restrict__ wgb,
    float* __restrict__ dvec) {
  __shared__ float smem[64 * 68];
  const int idx = blockIdx.x;
  const int t = threadIdx.x;
  const int wave = t >> 6, lane = t & 63;
  if (idx < 1024) {
    // ---- cast b -> bf16 hi/lo (truncation, identical to old f8_hilo) + exact srow
    const int row = idx;  // global row over 4*256
    const float* src = bin + (size_t)row * NSP + t * 16;
    float sum = 0.f;
    unsigned short h16[16], l16[16];
#pragma unroll
    for (int i = 0; i < 4; ++i) {
      const float4 v = *(const float4*)(src + i * 4);
      const float vv[4] = {v.x, v.y, v.z, v.w};
      sum += v.x + v.y + v.z + v.w;
#pragma unroll
      for (int e = 0; e < 4; ++e) {
        const unsigned u = __float_as_uint(vv[e]);
        h16[i * 4 + e] = (unsigned short)(u >> 16);
        const float hf = __uint_as_float(u & 0xffff0000u);
        l16[i * 4 + e] = (unsigned short)(__float_as_uint(vv[e] - hf) >> 16);
      }
    }
    unsigned short* dh = (unsigned short*)bhi + (size_t)row * NSP + t * 16;
    unsigned short* dl = (unsigned short*)blo + (size_t)row * NSP + t * 16;
    *(u16x8*)dh = *(u16x8*)&h16[0];
    *(u16x8*)(dh + 8) = *(u16x8*)&h16[8];
    *(u16x8*)dl = *(u16x8*)&l16[0];
    *(u16x8*)(dl + 8) = *(u16x8*)&l16[8];
#pragma unroll
    for (int off = 32; off; off >>= 1) sum += __shfl_down(sum, off);
    if (lane == 0) smem[wave] = sum;
    __syncthreads();
    if (t == 0) srow[row] = smem[0] + smem[1] + smem[2] + smem[3];
  } else if (idx < 2048) {
    // ---- cast a -> bf16 transposed: at[b][n][c] ----
    const int p = idx - 1024;
    const int n0 = (p & 63) * 64, c0 = ((p >> 6) & 3) * 64, b = p >> 8;
    float (*tile)[68] = (float(*)[68])smem;
    const int cr = t >> 4, nq = (t & 15) << 2;
    const float* src = a + ((size_t)(b * CCH + c0)) * NSP + n0;
#pragma unroll
    for (int s = 0; s < 4; ++s) {
      const float4 v = *(const float4*)(src + (size_t)(cr + s * 16) * NSP + nq);
      *(float4*)&tile[cr + s * 16][nq] = v;
    }
    __syncthreads();
    const int n = t >> 2, cq = (t & 3) << 4;
    __bf16 outv[16];
#pragma unroll
    for (int i = 0; i < 16; ++i) outv[i] = (__bf16)tile[cq + i][n];
    __bf16* dst = at + ((size_t)(b * NSP + n0 + n)) * CCH + c0 + cq;
    *(bf16x8*)dst = *(bf16x8*)&outv[0];
    *(bf16x8*)(dst + 8) = *(bf16x8*)&outv[8];
  } else if (idx < 2080) {
    // ---- prep: Wg = W_w @ g_w (z=0) ; PTt = theta_w^T @ phi_w (z=1) ----
    const int p = idx - 2048;
    const int zsel = p >> 4, rem = p & 15;
    const int m0 = (rem >> 2) * 64, n0 = (rem & 3) * 64;
    float (*As)[68] = (float(*)[68])smem;
    float (*Bs)[68] = (float(*)[68])(smem + 16 * 68);
    const int ty = t >> 4, tx = t & 15;
    float acc[4][4] = {};
    if (zsel == 0) {
      float4 ar = fetch_tr(W_w, CIN, m0, 0, t);
      float4 br = fetch_dir(g_w, CCH, 0, n0, t);
      for (int kt = 0; kt < 8; ++kt) {
        stash_tr(As, ar, t); stash_dir(Bs, br, t);
        __syncthreads();
        if (kt < 7) { ar = fetch_tr(W_w, CIN, m0, (kt + 1) * 16, t);
                      br = fetch_dir(g_w, CCH, (kt + 1) * 16, n0, t); }
        mm16(As, Bs, acc, ty, tx);
        __syncthreads();
      }
#pragma unroll
      for (int i = 0; i < 4; ++i) {
        const size_t off = (size_t)(m0 + (ty << 2) + i) * 256 + n0 + (tx << 2);
        *(float4*)(Wg + off) = make_float4(acc[i][0], acc[i][1], acc[i][2], acc[i][3]);
        __bf16 h4[4], l4[4];
#pragma unroll
        for (int j = 0; j < 4; ++j) {
          const __bf16 h = (__bf16)acc[i][j];
          h4[j] = h; l4[j] = (__bf16)(acc[i][j] - (float)h);
        }
        *(bf16x4*)(Wghi + off) = *(bf16x4*)h4;
        *(bf16x4*)(Wglo + off) = *(bf16x4*)l4;
      }
    } else {
      float4 ar = fetch_dir(theta_w, CCH, 0, m0, t);   // swapped: computes PT^T
      float4 br = fetch_dir(phi_w, CCH, 0, n0, t);
      for (int kt = 0; kt < 8; ++kt) {
        stash_dir(As, ar, t); stash_dir(Bs, br, t);
        __syncthreads();
        if (kt < 7) { ar = fetch_dir(theta_w, CCH, (kt + 1) * 16, m0, t);
                      br = fetch_dir(phi_w, CCH, (kt + 1) * 16, n0, t); }
        mm16(As, Bs, acc, ty, tx);
        __syncthreads();
      }
#pragma unroll
      for (int i = 0; i < 4; ++i) {
        const size_t off = (size_t)(m0 + (ty << 2) + i) * 256 + n0 + (tx << 2);
        __bf16 h4[4], l4[4];
#pragma unroll
        for (int j = 0; j < 4; ++j) {
          const __bf16 h = (__bf16)acc[i][j];
          h4[j] = h; l4[j] = (__bf16)(acc[i][j] - (float)h);
        }
        *(bf16x4*)(PTthi + off) = *(bf16x4*)h4;
        *(bf16x4*)(PTtlo + off) = *(bf16x4*)l4;
      }
    }
  } else if (idx == 2080) {
    // ---- vb[c] = phi_w^T @ theta_b ; d1 = phi_b . theta_b ----
    float* tb_s = smem;
    float* pb_s = smem + 128;
    if (t < 128) { tb_s[t] = theta_b[t]; pb_s[t] = phi_b[t]; }
    __syncthreads();
    float acc = 0.f;
#pragma unroll 8
    for (int i = 0; i < 128; ++i) acc += phi_w[(size_t)i * 256 + t] * tb_s[i];
    vb_g[t] = acc;
    if (t < 64) {
      float pv = pb_s[t] * tb_s[t] + pb_s[t + 64] * tb_s[t + 64];
      pv = wave_reduce(pv);
      if (t == 0) dvec[0] = pv;
    }
  } else if (idx == 2081) {
    // ---- vpt[c] = phi_b^T @ theta_w ----
    float* pb_s = smem;
    if (t < 128) pb_s[t] = phi_b[t];
    __syncthreads();
    float acc = 0.f;
#pragma unroll 8
    for (int i = 0; i < 128; ++i) acc += pb_s[i] * theta_w[(size_t)i * 256 + t];
    vpt[t] = acc;
  } else {
    // ---- wgb[o] = W_w[o] . g_b : 4 blocks x 64 outputs ----
    const int p = idx - 2082;
    float* gb_s = smem;
    if (t < 128) gb_s[t] = g_b[t];
    __syncthreads();
    const float2 gv = *(const float2*)&gb_s[lane * 2];
    for (int i = 0; i < 16; ++i) {
      const int o = p * 64 + wave * 16 + i;
      const float2 r = *(const float2*)(W_w + (size_t)o * 128 + lane * 2);
      float v = fmaf(r.x, gv.x, r.y * gv.y);
      v = wave_reduce(v);
      if (lane == 0) wgb[o] = v;
    }
  }
}

// ===== k1: gram partials (0..511, LDS-staged bf16 MFMA) + aux (512..575) ========
// Gram: kc-split = 8: per block (jt,it,kc,batch): G_tile[64x64] over k=512.
// LDS tiles hold a 32-k slab as 8 chunks/row of 16B: chunk ch = (h*4 + j) ^ (r&7).
// Swizzle applied on the per-lane GLOBAL source address (LDS dest of
// global_load_lds is linear), undone identically on ds_read -> bit-identical.
// Aux (moved from redw2 — depends only on prep outputs, consumed by wout):
// Wgs = Wg@s ; sPTv = PTt@s ; d2 = s.vb. Overlaps with gram blocks.
__global__ __launch_bounds__(256) void gram_kernel(
    const __bf16* __restrict__ bhi, const __bf16* __restrict__ blo,
    float* __restrict__ Gpart,
    const float* __restrict__ srow, const float* __restrict__ Wg,
    const __bf16* __restrict__ PTthi, const __bf16* __restrict__ PTtlo,
    const float* __restrict__ vb_g,
    float* __restrict__ Wgs, float* __restrict__ sPTv, float* __restrict__ dvec) {
  __shared__ __bf16 At[2][64][64];
  __shared__ __bf16 Bt[2][64][64];
  const int idx = blockIdx.x;
  const int t = threadIdx.x;
  const int wave = t >> 6, lane = t & 63;
  if (idx < 512) {
    const int jt = idx & 3, it = (idx >> 2) & 3;
    const int z = idx >> 4, batch = z >> 3, kc = z & 7;
    const int m = lane & 15, q = lane >> 4;
    const size_t rowbase = (size_t)batch * CCH;
    const int colbase = kc * 512;
    // staging lane geometry (constant per lane): r_in_seg, chunk, unswizzled (h,j)
    const int rseg = lane >> 3, ch = lane & 7;
    const int u = ch ^ rseg;          // r&7 == rseg since segments are 8-row aligned
    const int h = u >> 2, j = u & 3;
    const __bf16* gsrc = h ? blo : bhi;

    auto stage = [&](int ph, int ks) {
#pragma unroll
      for (int c = 0; c < 4; ++c) {
        const int s = wave * 4 + c;     // 0..15: 0-7 A-tile KBs, 8-15 B-tile KBs
        const int isB = s >> 3;
        const int kb = s & 7;
        const int grow = (isB ? jt : it) * 64 + kb * 8 + rseg;
        const __bf16* gp = gsrc + (rowbase + (size_t)grow) * NSP +
                           colbase + ks * 32 + j * 8;
        const __bf16* lp = isB ? &Bt[ph][kb * 8][0] : &At[ph][kb * 8][0];
        __builtin_amdgcn_global_load_lds((gu32*)(const void*)gp,
                                         (lu32*)(void*)lp, 16, 0, 0);
      }
    };

    f32x4 acc[4] = {};
    const int chA = q ^ (m & 7);      // hi chunk for this lane's rows (r&7 == m&7)
    stage(0, 0);
    int ph = 0;
    for (int ks = 0; ks < 16; ++ks) {
      __syncthreads();                // stage(ks) visible (vmcnt drained at barrier)
      if (ks < 15) stage(ph ^ 1, ks + 1);
      const bf16x8 ah = *(const bf16x8*)&At[ph][wave * 16 + m][chA * 8];
      const bf16x8 al = *(const bf16x8*)&At[ph][wave * 16 + m][(chA ^ 4) * 8];
#pragma unroll
      for (int t4 = 0; t4 < 4; ++t4) {
        const bf16x8 bh = *(const bf16x8*)&Bt[ph][t4 * 16 + m][chA * 8];
        const bf16x8 bl = *(const bf16x8*)&Bt[ph][t4 * 16 + m][(chA ^ 4) * 8];
        acc[t4] = __builtin_amdgcn_mfma_f32_16x16x32_bf16(ah, bh, acc[t4], 0, 0, 0);
        acc[t4] = __builtin_amdgcn_mfma_f32_16x16x32_bf16(ah, bl, acc[t4], 0, 0, 0);
        acc[t4] = __builtin_amdgcn_mfma_f32_16x16x32_bf16(al, bh, acc[t4], 0, 0, 0);
      }
      ph ^= 1;
    }
    float* Gp = Gpart + ((size_t)(kc * 4 + batch)) * 65536;
#pragma unroll
    for (int t4 = 0; t4 < 4; ++t4)
#pragma unroll
      for (int r = 0; r < 4; ++r)
        Gp[(size_t)(it * 64 + wave * 16 + q * 4 + r) * 256 + jt * 64 + t4 * 16 + m] =
            acc[t4][r];
  } else {
    // ---- aux: Wgs = Wg@s ; sPTv = PTt@s ; d2 = s.vb ----
    float* lds = (float*)&At[0][0][0];
    const int p = idx - 512;
    const int b = p >> 4, seg = p & 15;
    lds[t] = srow[b * 256 + t];
    __syncthreads();
    const float4 sv = *(const float4*)&lds[lane * 4];
    for (int i = wave; i < 16; i += 4) {
      const int o = seg * 16 + i;
      const float4 r = *(const float4*)(Wg + (size_t)o * 256 + lane * 4);
      float v = fmaf(r.x, sv.x, fmaf(r.y, sv.y, fmaf(r.z, sv.z, r.w * sv.w)));
      v = wave_reduce(v);
      if (lane == 0) Wgs[b * 256 + o] = v;
    }
    for (int i = wave; i < 16; i += 4) {
      const int c = seg * 16 + i;
      const bf16x4 ph = *(const bf16x4*)(PTthi + (size_t)c * 256 + lane * 4);
      const bf16x4 pl = *(const bf16x4*)(PTtlo + (size_t)c * 256 + lane * 4);
      const float svv[4] = {sv.x, sv.y, sv.z, sv.w};
      float v = 0.f;
#pragma unroll
      for (int e = 0; e < 4; ++e) v += ((float)ph[e] + (float)pl[e]) * svv[e];
      v = wave_reduce(v);
      if (lane == 0) sPTv[b * 256 + c] = v;
    }
    if (seg == 0 && wave == 0) {
      const float4 vbv = *(const float4*)(vb_g + lane * 4);
      float v = fmaf(vbv.x, sv.x, fmaf(vbv.y, sv.y, fmaf(vbv.z, sv.z, vbv.w * sv.w)));
      v = wave_reduce(v);
      if (lane == 0) dvec[1 + b] = v;
    }
  }
}

// ===== k2: fused reduce+W2, 1x Gpart read (64 blocks) ===========================
__global__ __launch_bounds__(256) void redw2_kernel(
    const float* __restrict__ Gpart, const float* __restrict__ vb_g,
    float* __restrict__ t2_g,
    const __bf16* __restrict__ Wghi, const __bf16* __restrict__ Wglo,
    __bf16* __restrict__ W2hi, __bf16* __restrict__ W2lo) {
  const int blk = blockIdx.x;
  const int t = threadIdx.x;
  const int wave = t >> 6, lane = t & 63;
  __shared__ __bf16 Gsh[16][264], Gsl[16][264];   // +8 pad: 2-way banks only
  const int b = blk >> 4, nt = blk & 15;
  // ---- phase A: reduce 16 rows x 256 cols over 8 partials (read once) ----
  const int rr = t >> 4;
  const int c0 = (t & 15) * 16;
  f32x4 s[4] = {};
#pragma unroll
  for (int p = 0; p < 8; ++p) {
    const float* src = Gpart + (((size_t)(p * 4 + b)) << 16) +
                       (size_t)(nt * 16 + rr) * 256 + c0;
#pragma unroll
    for (int e = 0; e < 4; ++e) s[e] += *(const f32x4*)(src + e * 4);
  }
  {
    float part = 0.f;
#pragma unroll
    for (int e = 0; e < 4; ++e) {
      const float4 vv = *(const float4*)(vb_g + c0 + e * 4);
      part += s[e][0] * vv.x + s[e][1] * vv.y + s[e][2] * vv.z + s[e][3] * vv.w;
    }
#pragma unroll
    for (int off = 8; off; off >>= 1) part += __shfl_down(part, off);
    if ((t & 15) == 0) t2_g[b * 256 + nt * 16 + rr] = part;
  }
  __bf16 h8[16], l8[16];
#pragma unroll
  for (int e = 0; e < 16; ++e) {
    const float x = s[e >> 2][e & 3];
    const __bf16 h = (__bf16)x;
    h8[e] = h; l8[e] = (__bf16)(x - (float)h);
  }
  *(bf16x8*)&Gsh[rr][c0] = *(bf16x8*)&h8[0];
  *(bf16x8*)&Gsh[rr][c0 + 8] = *(bf16x8*)&h8[8];
  *(bf16x8*)&Gsl[rr][c0] = *(bf16x8*)&l8[0];
  *(bf16x8*)&Gsl[rr][c0 + 8] = *(bf16x8*)&l8[8];
  __syncthreads();
  // ---- phase B: 4 independent W2 tiles per wave (mt = i*4 + wave) ----
  const int m = lane & 15, q = lane >> 4;
  f32x4 acc[4] = {};
#pragma unroll
  for (int ks = 0; ks < 8; ++ks) {
    const int k = ks * 32 + q * 8;
    const bf16x8 bh = *(const bf16x8*)&Gsh[m][k];
    const bf16x8 bl = *(const bf16x8*)&Gsl[m][k];
#pragma unroll
    for (int i = 0; i < 4; ++i) {
      const int mt = i * 4 + wave;
      const bf16x8 ah = *(const bf16x8*)(Wghi + (size_t)(mt * 16 + m) * 256 + k);
      const bf16x8 al = *(const bf16x8*)(Wglo + (size_t)(mt * 16 + m) * 256 + k);
      acc[i] = __builtin_amdgcn_mfma_f32_16x16x32_bf16(ah, bh, acc[i], 0, 0, 0);
      acc[i] = __builtin_amdgcn_mfma_f32_16x16x32_bf16(ah, bl, acc[i], 0, 0, 0);
      acc[i] = __builtin_amdgcn_mfma_f32_16x16x32_bf16(al, bh, acc[i], 0, 0, 0);
    }
  }
#pragma unroll
  for (int i = 0; i < 4; ++i) {
    const int mt = i * 4 + wave;
#pragma unroll
    for (int r = 0; r < 4; ++r) {
      const size_t off = ((size_t)b << 16) + (size_t)(mt * 16 + q * 4 + r) * 256 +
                         nt * 16 + m;
      const float v = acc[i][r];
      const __bf16 h = (__bf16)v;
      W2hi[off] = h;
      W2lo[off] = (__bf16)(v - (float)h);
    }
  }
}

// ===== k3: W_out (blocks 0..63, 4 tiles/wave) + bias chain (64..79) =============
__global__ __launch_bounds__(256) void wout_mfma_kernel(
    const __bf16* __restrict__ W2hi, const __bf16* __restrict__ W2lo,
    const __bf16* __restrict__ PTthi, const __bf16* __restrict__ PTtlo,
    const float* __restrict__ Wgs, const float* __restrict__ sPT,
    const float* __restrict__ wgb, const float* __restrict__ vpt,
    const float* __restrict__ Wg, const float* __restrict__ t2_g,
    const float* __restrict__ dvec,
    const float* __restrict__ bn_gamma, const float* __restrict__ bn_beta,
    const float* __restrict__ bn_mean, const float* __restrict__ bn_var,
    __bf16* __restrict__ Whi, __bf16* __restrict__ Wlo,
    float* __restrict__ bias_out) {
  const int blk = blockIdx.x;
  const int t = threadIdx.x;
  const int wave = t >> 6, lane = t & 63;
  if (blk < 64) {
    const int batch = blk >> 4, nt = blk & 15;
    const int m = lane & 15, q = lane >> 4;
    const __bf16* bh_p = PTthi + (size_t)(nt * 16 + m) * 256;   // PTt row = PT column
    const __bf16* bl_p = PTtlo + (size_t)(nt * 16 + m) * 256;
    const __bf16* w2h = W2hi + (size_t)batch * 65536;
    const __bf16* w2l = W2lo + (size_t)batch * 65536;
    f32x4 acc[4] = {};
#pragma unroll
    for (int ks = 0; ks < 8; ++ks) {
      const int k = ks * 32 + q * 8;
      const bf16x8 bh = *(const bf16x8*)(bh_p + k);
      const bf16x8 bl = *(const bf16x8*)(bl_p + k);
#pragma unroll
      for (int i = 0; i < 4; ++i) {
        const int mt = i * 4 + wave;
        const bf16x8 ah = *(const bf16x8*)(w2h + (size_t)(mt * 16 + m) * 256 + k);
        const bf16x8 al = *(const bf16x8*)(w2l + (size_t)(mt * 16 + m) * 256 + k);
        acc[i] = __builtin_amdgcn_mfma_f32_16x16x32_bf16(ah, bh, acc[i], 0, 0, 0);
        acc[i] = __builtin_amdgcn_mfma_f32_16x16x32_bf16(ah, bl, acc[i], 0, 0, 0);
        acc[i] = __builtin_amdgcn_mfma_f32_16x16x32_bf16(al, bh, acc[i], 0, 0, 0);
      }
    }
    const float invN = 1.0f / 4096.0f;
    const int c = nt * 16 + m;
    const float vpt_c = vpt[c];
    const float sPT_c = sPT[batch * 256 + c];
#pragma unroll
    for (int i = 0; i < 4; ++i) {
      const int mt = i * 4 + wave;
#pragma unroll
      for (int r = 0; r < 4; ++r) {
        const int o = mt * 16 + q * 4 + r;
        const float sc = bn_gamma[o] * rsqrtf(bn_var[o] + BN_EPS);
        const float w = sc * ((acc[i][r] + Wgs[batch * 256 + o] * vpt_c + wgb[o] * sPT_c) * invN +
                              wgb[o] * vpt_c);
        const size_t off = (size_t)batch * 65536 + (size_t)o * 256 + c;
        const __bf16 h = (__bf16)w;
        Whi[off] = h;
        Wlo[off] = (__bf16)(w - (float)h);
      }
    }
  } else {
    // ---- bias chain: bias = sc*((Wg@t2 + Wgs*d1 + wgb*(d2+N*d1))/N - mean)+beta
    const int p = blk - 64;
    const int b = p >> 2, quarter = p & 3;
    __shared__ float t2s[256];
    t2s[t] = t2_g[b * 256 + t];
    __syncthreads();
    const float d1 = dvec[0], d2 = dvec[1 + b];
    const float invN = 1.0f / 4096.0f;
    const float4 tv = *(const float4*)&t2s[lane * 4];
    for (int it = 0; it < 16; ++it) {
      const int o = quarter * 64 + wave * 16 + it;
      const float4 r = *(const float4*)(Wg + (size_t)o * 256 + lane * 4);
      float v = fmaf(r.x, tv.x, fmaf(r.y, tv.y, fmaf(r.z, tv.z, r.w * tv.w)));
      v = wave_reduce(v);
      if (lane == 0) {
        const float bias_full = (v + Wgs[b * 256 + o] * d1 +
                                 wgb[o] * (d2 + 4096.0f * d1)) * invN;
        const float sc = bn_gamma[o] * rsqrtf(bn_var[o] + BN_EPS);
        bias_out[b * 256 + o] = sc * (bias_full - bn_mean[o]) + bn_beta[o];
      }
    }
  }
}

// ===== k4: out[b] = W_out[b] @ a[b] + bias — register-resident W ================
// Block (ng,mt,b): wave's W rows (hi+lo) loaded ONCE into 64 VGPRs, then 2
// n-subtiles of pure {at-load -> MFMA}, no barriers. NO launch_bounds VGPR cap
// (the ,2 cap in the previous round forced spills). Grid 512 -> 2 blocks/CU.
__global__ __launch_bounds__(256) void out_mfma_kernel(const __bf16* __restrict__ Whi,
                                                       const __bf16* __restrict__ Wlo,
                                                       const __bf16* __restrict__ at,
                                                       const float* __restrict__ bias_out,
                                                       float* __restrict__ out) {
  const int ng = blockIdx.x, mt = blockIdx.y, b = blockIdx.z;
  const int wave = threadIdx.x >> 6, lane = threadIdx.x & 63;
  const int m = lane & 15, q = lane >> 4;
  const int o = mt * 64 + wave * 16 + m;
  const __bf16* wh = Whi + (size_t)b * 65536 + (size_t)o * 256;
  const __bf16* wl = Wlo + (size_t)b * 65536 + (size_t)o * 256;
  bf16x8 ah[8], al[8];
#pragma unroll
  for (int ks = 0; ks < 8; ++ks) {
    ah[ks] = *(const bf16x8*)(wh + ks * 32 + q * 8);
    al[ks] = *(const bf16x8*)(wl + ks * 32 + q * 8);
  }
  float bo[4];
#pragma unroll
  for (int r = 0; r < 4; ++r)
    bo[r] = bias_out[b * 256 + mt * 64 + wave * 16 + q * 4 + r];
  float* ob = out + (size_t)b * CCH * NSP;
#pragma unroll
  for (int nt4 = 0; nt4 < 2; ++nt4) {
    const __bf16* atb = at + ((size_t)b * NSP + ng * 128 + nt4 * 64) * CCH;
    f32x4 acc[4] = {};
#pragma unroll
    for (int ks = 0; ks < 8; ++ks) {
      const int k = ks * 32 + q * 8;
#pragma unroll
      for (int t4 = 0; t4 < 4; ++t4) {
        const bf16x8 bh = *(const bf16x8*)(atb + (size_t)(t4 * 16 + m) * 256 + k);
        acc[t4] = __builtin_amdgcn_mfma_f32_16x16x32_bf16(ah[ks], bh, acc[t4], 0, 0, 0);
        acc[t4] = __builtin_amdgcn_mfma_f32_16x16x32_bf16(al[ks], bh, acc[t4], 0, 0, 0);
      }
    }
#pragma unroll
    for (int r = 0; r < 4; ++r) {
      const int orow = mt * 64 + wave * 16 + q * 4 + r;
#pragma unroll
      for (int t4 = 0; t4 < 4; ++t4)
        ob[(size_t)orow * NSP + ng * 128 + nt4 * 64 + t4 * 16 + m] = acc[t4][r] + bo[r];
    }
  }
}

extern "C" void kernel_launch(void* const* d_in, const int* in_sizes, int n_in,
                              void* d_out, int out_size, void* d_ws, size_t ws_size,
                              hipStream_t stream) {
  (void)in_sizes; (void)n_in; (void)out_size; (void)ws_size;
  const float* a       = (const float*)d_in[0];
  const float* bI      = (const float*)d_in[1];
  const float* theta_w = (const float*)d_in[2];
  const float* theta_b = (const float*)d_in[3];
  const float* phi_w   = (const float*)d_in[4];
  const float* phi_b   = (const float*)d_in[5];
  const float* g_w     = (const float*)d_in[6];
  const float* g_b     = (const float*)d_in[7];
  const float* W_w     = (const float*)d_in[8];
  const float* bn_gamma= (const float*)d_in[9];
  const float* bn_beta = (const float*)d_in[10];
  const float* bn_mean = (const float*)d_in[11];
  const float* bn_var  = (const float*)d_in[12];
  float* out = (float*)d_out;
  float* ws  = (float*)d_ws;

  // fp32 region (float offsets)
  float* Gpart    = ws;                  // 8 MB used (kc-split 8)
  float* srow     = ws + 4194304;        // 1024
  float* Wg       = ws + 4195328;        // 65536
  float* bias_out = ws + 4260864;        // 1024
  float* Wgs      = ws + 4261888;        // 1024
  float* sPTv     = ws + 4262912;        // 1024
  float* wgb      = ws + 4263936;        // 256
  float* vpt      = ws + 4264192;        // 256
  float* vb_g     = ws + 4264448;        // 256
  float* t2_g     = ws + 4264704;        // 1024
  float* dvec     = ws + 4265728;        // 8 (pad to 256)
  // bf16 region
  __bf16* at    = (__bf16*)(ws + 4265984);   // 8 MB
  __bf16* Wghi  = (__bf16*)(ws + 6363136);   // 128 KB each below
  __bf16* Wglo  = (__bf16*)(ws + 6395904);
  __bf16* PTthi = (__bf16*)(ws + 6428672);
  __bf16* PTtlo = (__bf16*)(ws + 6461440);
  __bf16* W2hi  = (__bf16*)(ws + 6494208);   // 512 KB each below
  __bf16* W2lo  = (__bf16*)(ws + 6625280);
  __bf16* Whi   = (__bf16*)(ws + 6756352);
  __bf16* Wlo   = (__bf16*)(ws + 6887424);
  __bf16* bhi   = (__bf16*)(ws + 7018496);   // 8 MB
  __bf16* blo   = (__bf16*)(ws + 9115648);   // 8 MB, end ~44.9 MB

  prep_kernel<<<dim3(2086), dim3(256), 0, stream>>>(bI, a, W_w, g_w, phi_w, theta_w,
                                                    phi_b, theta_b, g_b,
                                                    bhi, blo, srow, Wg, Wghi, Wglo,
                                                    PTthi, PTtlo, at,
                                                    vb_g, vpt, wgb, dvec);
  gram_kernel<<<dim3(576), dim3(256), 0, stream>>>(bhi, blo, Gpart, srow, Wg,
                                                   PTthi, PTtlo, vb_g,
                                                   Wgs, sPTv, dvec);
  redw2_kernel<<<dim3(64), dim3(256), 0, stream>>>(Gpart, vb_g, t2_g,
                                                   Wghi, Wglo, W2hi, W2lo);
  wout_mfma_kernel<<<dim3(80), dim3(256), 0, stream>>>(W2hi, W2lo, PTthi, PTtlo,
                                                       Wgs, sPTv, wgb, vpt, Wg, t2_g,
                                                       dvec, bn_gamma, bn_beta, bn_mean,
                                                       bn_var, Whi, Wlo, bias_out);
  out_mfma_kernel<<<dim3(32, 4, 4), dim3(256), 0, stream>>>(Whi, Wlo, at, bias_out, out);
}

// Round 5
// 170.433 us; speedup vs baseline: 1.1944x; 1.0277x over previous
//
#include <hip/hip_runtime.h>
#include <hip/hip_bf16.h>

#define NSP 4096   // H*W
#define CCH 256    // C
#define CIN 128    // Ci
#define BN_EPS 1e-5f

typedef __bf16 bf16x8 __attribute__((ext_vector_type(8)));
typedef __bf16 bf16x4 __attribute__((ext_vector_type(4)));
typedef float f32x4 __attribute__((ext_vector_type(4)));
typedef unsigned short u16x8 __attribute__((ext_vector_type(8)));

typedef const __attribute__((address_space(1))) unsigned int gu32;
typedef __attribute__((address_space(3))) unsigned int lu32;

// upper-triangle tile enumeration for the symmetric Gram (10 of 16 tiles)
__constant__ int IT10[10] = {0,0,0,0,1,1,1,2,2,3};
__constant__ int JT10[10] = {0,1,2,3,1,2,3,2,3,3};

// ================= fp32 tile helpers (prep only) =================================

__device__ __forceinline__ float4 fetch_tr(const float* __restrict__ A, int lda, int m0,
                                           int k0, int tid) {
  const int r = tid >> 2, kq = (tid & 3) << 2;
  return *(const float4*)(A + (size_t)(m0 + r) * lda + k0 + kq);
}
__device__ __forceinline__ void stash_tr(float (*As)[68], float4 v, int tid) {
  const int r = tid >> 2, kq = (tid & 3) << 2;
  As[kq + 0][r] = v.x; As[kq + 1][r] = v.y; As[kq + 2][r] = v.z; As[kq + 3][r] = v.w;
}
__device__ __forceinline__ float4 fetch_dir(const float* __restrict__ B, int ldb, int k0,
                                            int n0, int tid) {
  const int kr = tid >> 4, nq = (tid & 15) << 2;
  return *(const float4*)(B + (size_t)(k0 + kr) * ldb + n0 + nq);
}
__device__ __forceinline__ void stash_dir(float (*Bs)[68], float4 v, int tid) {
  const int kr = tid >> 4, nq = (tid & 15) << 2;
  *(float4*)(&Bs[kr][nq]) = v;
}

__device__ __forceinline__ void mm16(const float (*As)[68], const float (*Bs)[68],
                                     float acc[4][4], int ty, int tx) {
#pragma unroll
  for (int kk = 0; kk < 16; ++kk) {
    const float4 av = *(const float4*)(&As[kk][ty << 2]);
    const float4 bv = *(const float4*)(&Bs[kk][tx << 2]);
    const float ar[4] = {av.x, av.y, av.z, av.w};
    const float br[4] = {bv.x, bv.y, bv.z, bv.w};
#pragma unroll
    for (int i = 0; i < 4; ++i)
#pragma unroll
      for (int j = 0; j < 4; ++j) acc[i][j] += ar[i] * br[j];
  }
}

__device__ __forceinline__ float wave_reduce(float v) {
#pragma unroll
  for (int off = 32; off; off >>= 1) v += __shfl_down(v, off);
  return v;  // valid in lane 0
}

// ===== k0: all independent prep in one dispatch =================================
// cast_b+srow(0..1023) + cast_a(1024..2047) + prep(2048..2079) + vb/d1(2080)
// + vpt(2081) + wgb(2082..2085)
__global__ __launch_bounds__(256) void prep_kernel(
    const float* __restrict__ bin, const float* __restrict__ a,
    const float* __restrict__ W_w, const float* __restrict__ g_w,
    const float* __restrict__ phi_w, const float* __restrict__ theta_w,
    const float* __restrict__ phi_b, const float* __restrict__ theta_b,
    const float* __restrict__ g_b,
    __bf16* __restrict__ bhi, __bf16* __restrict__ blo,
    float* __restrict__ srow,
    float* __restrict__ Wg, __bf16* __restrict__ Wghi, __bf16* __restrict__ Wglo,
    __bf16* __restrict__ PTthi, __bf16* __restrict__ PTtlo,
    __bf16* __restrict__ at,
    float* __restrict__ vb_g, float* __restrict__ vpt, float* __restrict__ wgb,
    float* __restrict__ dvec) {
  __shared__ float smem[64 * 68];
  const int idx = blockIdx.x;
  const int t = threadIdx.x;
  const int wave = t >> 6, lane = t & 63;
  if (idx < 1024) {
    // ---- cast b -> bf16 hi/lo (truncation, identical to old f8_hilo) + exact srow
    const int row = idx;  // global row over 4*256
    const float* src = bin + (size_t)row * NSP + t * 16;
    float sum = 0.f;
    unsigned short h16[16], l16[16];
#pragma unroll
    for (int i = 0; i < 4; ++i) {
      const float4 v = *(const float4*)(src + i * 4);
      const float vv[4] = {v.x, v.y, v.z, v.w};
      sum += v.x + v.y + v.z + v.w;
#pragma unroll
      for (int e = 0; e < 4; ++e) {
        const unsigned u = __float_as_uint(vv[e]);
        h16[i * 4 + e] = (unsigned short)(u >> 16);
        const float hf = __uint_as_float(u & 0xffff0000u);
        l16[i * 4 + e] = (unsigned short)(__float_as_uint(vv[e] - hf) >> 16);
      }
    }
    unsigned short* dh = (unsigned short*)bhi + (size_t)row * NSP + t * 16;
    unsigned short* dl = (unsigned short*)blo + (size_t)row * NSP + t * 16;
    *(u16x8*)dh = *(u16x8*)&h16[0];
    *(u16x8*)(dh + 8) = *(u16x8*)&h16[8];
    *(u16x8*)dl = *(u16x8*)&l16[0];
    *(u16x8*)(dl + 8) = *(u16x8*)&l16[8];
#pragma unroll
    for (int off = 32; off; off >>= 1) sum += __shfl_down(sum, off);
    if (lane == 0) smem[wave] = sum;
    __syncthreads();
    if (t == 0) srow[row] = smem[0] + smem[1] + smem[2] + smem[3];
  } else if (idx < 2048) {
    // ---- cast a -> bf16 transposed: at[b][n][c] ----
    const int p = idx - 1024;
    const int n0 = (p & 63) * 64, c0 = ((p >> 6) & 3) * 64, b = p >> 8;
    float (*tile)[68] = (float(*)[68])smem;
    const int cr = t >> 4, nq = (t & 15) << 2;
    const float* src = a + ((size_t)(b * CCH + c0)) * NSP + n0;
#pragma unroll
    for (int s = 0; s < 4; ++s) {
      const float4 v = *(const float4*)(src + (size_t)(cr + s * 16) * NSP + nq);
      *(float4*)&tile[cr + s * 16][nq] = v;
    }
    __syncthreads();
    const int n = t >> 2, cq = (t & 3) << 4;
    __bf16 outv[16];
#pragma unroll
    for (int i = 0; i < 16; ++i) outv[i] = (__bf16)tile[cq + i][n];
    __bf16* dst = at + ((size_t)(b * NSP + n0 + n)) * CCH + c0 + cq;
    *(bf16x8*)dst = *(bf16x8*)&outv[0];
    *(bf16x8*)(dst + 8) = *(bf16x8*)&outv[8];
  } else if (idx < 2080) {
    // ---- prep: Wg = W_w @ g_w (z=0) ; PTt = theta_w^T @ phi_w (z=1) ----
    const int p = idx - 2048;
    const int zsel = p >> 4, rem = p & 15;
    const int m0 = (rem >> 2) * 64, n0 = (rem & 3) * 64;
    float (*As)[68] = (float(*)[68])smem;
    float (*Bs)[68] = (float(*)[68])(smem + 16 * 68);
    const int ty = t >> 4, tx = t & 15;
    float acc[4][4] = {};
    if (zsel == 0) {
      float4 ar = fetch_tr(W_w, CIN, m0, 0, t);
      float4 br = fetch_dir(g_w, CCH, 0, n0, t);
      for (int kt = 0; kt < 8; ++kt) {
        stash_tr(As, ar, t); stash_dir(Bs, br, t);
        __syncthreads();
        if (kt < 7) { ar = fetch_tr(W_w, CIN, m0, (kt + 1) * 16, t);
                      br = fetch_dir(g_w, CCH, (kt + 1) * 16, n0, t); }
        mm16(As, Bs, acc, ty, tx);
        __syncthreads();
      }
#pragma unroll
      for (int i = 0; i < 4; ++i) {
        const size_t off = (size_t)(m0 + (ty << 2) + i) * 256 + n0 + (tx << 2);
        *(float4*)(Wg + off) = make_float4(acc[i][0], acc[i][1], acc[i][2], acc[i][3]);
        __bf16 h4[4], l4[4];
#pragma unroll
        for (int j = 0; j < 4; ++j) {
          const __bf16 h = (__bf16)acc[i][j];
          h4[j] = h; l4[j] = (__bf16)(acc[i][j] - (float)h);
        }
        *(bf16x4*)(Wghi + off) = *(bf16x4*)h4;
        *(bf16x4*)(Wglo + off) = *(bf16x4*)l4;
      }
    } else {
      float4 ar = fetch_dir(theta_w, CCH, 0, m0, t);   // swapped: computes PT^T
      float4 br = fetch_dir(phi_w, CCH, 0, n0, t);
      for (int kt = 0; kt < 8; ++kt) {
        stash_dir(As, ar, t); stash_dir(Bs, br, t);
        __syncthreads();
        if (kt < 7) { ar = fetch_dir(theta_w, CCH, (kt + 1) * 16, m0, t);
                      br = fetch_dir(phi_w, CCH, (kt + 1) * 16, n0, t); }
        mm16(As, Bs, acc, ty, tx);
        __syncthreads();
      }
#pragma unroll
      for (int i = 0; i < 4; ++i) {
        const size_t off = (size_t)(m0 + (ty << 2) + i) * 256 + n0 + (tx << 2);
        __bf16 h4[4], l4[4];
#pragma unroll
        for (int j = 0; j < 4; ++j) {
          const __bf16 h = (__bf16)acc[i][j];
          h4[j] = h; l4[j] = (__bf16)(acc[i][j] - (float)h);
        }
        *(bf16x4*)(PTthi + off) = *(bf16x4*)h4;
        *(bf16x4*)(PTtlo + off) = *(bf16x4*)l4;
      }
    }
  } else if (idx == 2080) {
    // ---- vb[c] = phi_w^T @ theta_b ; d1 = phi_b . theta_b ----
    float* tb_s = smem;
    float* pb_s = smem + 128;
    if (t < 128) { tb_s[t] = theta_b[t]; pb_s[t] = phi_b[t]; }
    __syncthreads();
    float acc = 0.f;
#pragma unroll 8
    for (int i = 0; i < 128; ++i) acc += phi_w[(size_t)i * 256 + t] * tb_s[i];
    vb_g[t] = acc;
    if (t < 64) {
      float pv = pb_s[t] * tb_s[t] + pb_s[t + 64] * tb_s[t + 64];
      pv = wave_reduce(pv);
      if (t == 0) dvec[0] = pv;
    }
  } else if (idx == 2081) {
    // ---- vpt[c] = phi_b^T @ theta_w ----
    float* pb_s = smem;
    if (t < 128) pb_s[t] = phi_b[t];
    __syncthreads();
    float acc = 0.f;
#pragma unroll 8
    for (int i = 0; i < 128; ++i) acc += pb_s[i] * theta_w[(size_t)i * 256 + t];
    vpt[t] = acc;
  } else {
    // ---- wgb[o] = W_w[o] . g_b : 4 blocks x 64 outputs ----
    const int p = idx - 2082;
    float* gb_s = smem;
    if (t < 128) gb_s[t] = g_b[t];
    __syncthreads();
    const float2 gv = *(const float2*)&gb_s[lane * 2];
    for (int i = 0; i < 16; ++i) {
      const int o = p * 64 + wave * 16 + i;
      const float2 r = *(const float2*)(W_w + (size_t)o * 128 + lane * 2);
      float v = fmaf(r.x, gv.x, r.y * gv.y);
      v = wave_reduce(v);
      if (lane == 0) wgb[o] = v;
    }
  }
}

// ===== k1: gram partials, SYMMETRIC upper-triangle (0..319) + aux (320..383) ====
// G = B.B^T is symmetric and hh+hl+lh is symmetric under i<->j, so only the 10
// upper-triangle 64x64 tiles per (kc,batch) are computed; off-diagonal results
// are mirrored via an LDS transpose (coalesced write). Diagonal tiles skip the
// B-tile staging (read the A-tile twice — bit-identical data).
// XCD clustering: id = 8*(g2*10 + tile) + xcd pins each (kc=xcd, batch=g2)
// group's blocks to one XCD -> its 2 MB row-slice stays in that XCD's L2.
__global__ __launch_bounds__(256) void gram_kernel(
    const __bf16* __restrict__ bhi, const __bf16* __restrict__ blo,
    float* __restrict__ Gpart,
    const float* __restrict__ srow, const float* __restrict__ Wg,
    const __bf16* __restrict__ PTthi, const __bf16* __restrict__ PTtlo,
    const float* __restrict__ vb_g,
    float* __restrict__ Wgs, float* __restrict__ sPTv, float* __restrict__ dvec) {
  __shared__ __align__(16) __bf16 AtBt[2][2][64][64];   // [0]=A-tile, [1]=B-tile
  auto& At = AtBt[0];
  auto& Bt = AtBt[1];
  const int idx = blockIdx.x;
  const int t = threadIdx.x;
  const int wave = t >> 6, lane = t & 63;
  if (idx < 320) {
    const int kc = idx & 7;            // XCD id (== grp%8)
    const int rest = idx >> 3;         // 0..39
    const int tile = rest % 10;
    const int batch = rest / 10;       // 0..3
    const int it = IT10[tile], jt = JT10[tile];
    const bool diag = (it == jt);
    const int m = lane & 15, q = lane >> 4;
    const size_t rowbase = (size_t)batch * CCH;
    const int colbase = kc * 512;
    // staging lane geometry (constant per lane): r_in_seg, chunk, unswizzled (h,j)
    const int rseg = lane >> 3, ch = lane & 7;
    const int u = ch ^ rseg;          // r&7 == rseg since segments are 8-row aligned
    const int h = u >> 2, j = u & 3;
    const __bf16* gsrc = h ? blo : bhi;

    auto stage = [&](int ph, int ks) {
#pragma unroll
      for (int c = 0; c < 4; ++c) {
        const int s = wave * 4 + c;     // 0..15: 0-7 A-tile KBs, 8-15 B-tile KBs
        const int isB = s >> 3;
        if (diag && isB) continue;      // block-uniform: diag reads A twice
        const int kb = s & 7;
        const int grow = (isB ? jt : it) * 64 + kb * 8 + rseg;
        const __bf16* gp = gsrc + (rowbase + (size_t)grow) * NSP +
                           colbase + ks * 32 + j * 8;
        const __bf16* lp = isB ? &Bt[ph][kb * 8][0] : &At[ph][kb * 8][0];
        __builtin_amdgcn_global_load_lds((gu32*)(const void*)gp,
                                         (lu32*)(void*)lp, 16, 0, 0);
      }
    };

    f32x4 acc[4] = {};
    const int chA = q ^ (m & 7);      // hi chunk for this lane's rows (r&7 == m&7)
    stage(0, 0);
    int ph = 0;
    for (int ks = 0; ks < 16; ++ks) {
      __syncthreads();                // stage(ks) visible (vmcnt drained at barrier)
      if (ks < 15) stage(ph ^ 1, ks + 1);
      const bf16x8 ah = *(const bf16x8*)&At[ph][wave * 16 + m][chA * 8];
      const bf16x8 al = *(const bf16x8*)&At[ph][wave * 16 + m][(chA ^ 4) * 8];
      const __bf16 (*Bsrc)[64] = diag ? At[ph] : Bt[ph];
#pragma unroll
      for (int t4 = 0; t4 < 4; ++t4) {
        const bf16x8 bh = *(const bf16x8*)&Bsrc[t4 * 16 + m][chA * 8];
        const bf16x8 bl = *(const bf16x8*)&Bsrc[t4 * 16 + m][(chA ^ 4) * 8];
        acc[t4] = __builtin_amdgcn_mfma_f32_16x16x32_bf16(ah, bh, acc[t4], 0, 0, 0);
        acc[t4] = __builtin_amdgcn_mfma_f32_16x16x32_bf16(ah, bl, acc[t4], 0, 0, 0);
        acc[t4] = __builtin_amdgcn_mfma_f32_16x16x32_bf16(al, bh, acc[t4], 0, 0, 0);
      }
      ph ^= 1;
    }
    float* Gp = Gpart + ((size_t)(kc * 4 + batch)) * 65536;
#pragma unroll
    for (int t4 = 0; t4 < 4; ++t4)
#pragma unroll
      for (int r = 0; r < 4; ++r)
        Gp[(size_t)(it * 64 + wave * 16 + q * 4 + r) * 256 + jt * 64 + t4 * 16 + m] =
            acc[t4][r];
    if (!diag) {
      // mirror: G[jt-tile][it-tile] = transpose, via LDS (coalesced global write)
      __syncthreads();                          // all MFMA reads of AtBt done
      float* Tf = (float*)AtBt;                 // [64][68] fp32, 17.4 KB
#pragma unroll
      for (int t4 = 0; t4 < 4; ++t4)
#pragma unroll
        for (int r = 0; r < 4; ++r)
          Tf[(t4 * 16 + m) * 68 + wave * 16 + q * 4 + r] = acc[t4][r];
      __syncthreads();
      const int rr = t >> 2, cq = (t & 3) * 16;
      float* Gpt = Gp + (size_t)(jt * 64 + rr) * 256 + it * 64 + cq;
#pragma unroll
      for (int i = 0; i < 4; ++i)
        *(float4*)(Gpt + i * 4) = *(const float4*)&Tf[rr * 68 + cq + i * 4];
    }
  } else {
    // ---- aux: Wgs = Wg@s ; sPTv = PTt@s ; d2 = s.vb ----
    float* lds = (float*)AtBt;
    const int p = idx - 320;
    const int b = p >> 4, seg = p & 15;
    lds[t] = srow[b * 256 + t];
    __syncthreads();
    const float4 sv = *(const float4*)&lds[lane * 4];
    for (int i = wave; i < 16; i += 4) {
      const int o = seg * 16 + i;
      const float4 r = *(const float4*)(Wg + (size_t)o * 256 + lane * 4);
      float v = fmaf(r.x, sv.x, fmaf(r.y, sv.y, fmaf(r.z, sv.z, r.w * sv.w)));
      v = wave_reduce(v);
      if (lane == 0) Wgs[b * 256 + o] = v;
    }
    for (int i = wave; i < 16; i += 4) {
      const int c = seg * 16 + i;
      const bf16x4 ph = *(const bf16x4*)(PTthi + (size_t)c * 256 + lane * 4);
      const bf16x4 pl = *(const bf16x4*)(PTtlo + (size_t)c * 256 + lane * 4);
      const float svv[4] = {sv.x, sv.y, sv.z, sv.w};
      float v = 0.f;
#pragma unroll
      for (int e = 0; e < 4; ++e) v += ((float)ph[e] + (float)pl[e]) * svv[e];
      v = wave_reduce(v);
      if (lane == 0) sPTv[b * 256 + c] = v;
    }
    if (seg == 0 && wave == 0) {
      const float4 vbv = *(const float4*)(vb_g + lane * 4);
      float v = fmaf(vbv.x, sv.x, fmaf(vbv.y, sv.y, fmaf(vbv.z, sv.z, vbv.w * sv.w)));
      v = wave_reduce(v);
      if (lane == 0) dvec[1 + b] = v;
    }
  }
}

// ===== k2: fused reduce+W2, 1x Gpart read (64 blocks) ===========================
__global__ __launch_bounds__(256) void redw2_kernel(
    const float* __restrict__ Gpart, const float* __restrict__ vb_g,
    float* __restrict__ t2_g,
    const __bf16* __restrict__ Wghi, const __bf16* __restrict__ Wglo,
    __bf16* __restrict__ W2hi, __bf16* __restrict__ W2lo) {
  const int blk = blockIdx.x;
  const int t = threadIdx.x;
  const int wave = t >> 6, lane = t & 63;
  __shared__ __bf16 Gsh[16][264], Gsl[16][264];   // +8 pad: 2-way banks only
  const int b = blk >> 4, nt = blk & 15;
  // ---- phase A: reduce 16 rows x 256 cols over 8 partials (read once) ----
  const int rr = t >> 4;
  const int c0 = (t & 15) * 16;
  f32x4 s[4] = {};
#pragma unroll
  for (int p = 0; p < 8; ++p) {
    const float* src = Gpart + (((size_t)(p * 4 + b)) << 16) +
                       (size_t)(nt * 16 + rr) * 256 + c0;
#pragma unroll
    for (int e = 0; e < 4; ++e) s[e] += *(const f32x4*)(src + e * 4);
  }
  {
    float part = 0.f;
#pragma unroll
    for (int e = 0; e < 4; ++e) {
      const float4 vv = *(const float4*)(vb_g + c0 + e * 4);
      part += s[e][0] * vv.x + s[e][1] * vv.y + s[e][2] * vv.z + s[e][3] * vv.w;
    }
#pragma unroll
    for (int off = 8; off; off >>= 1) part += __shfl_down(part, off);
    if ((t & 15) == 0) t2_g[b * 256 + nt * 16 + rr] = part;
  }
  __bf16 h8[16], l8[16];
#pragma unroll
  for (int e = 0; e < 16; ++e) {
    const float x = s[e >> 2][e & 3];
    const __bf16 h = (__bf16)x;
    h8[e] = h; l8[e] = (__bf16)(x - (float)h);
  }
  *(bf16x8*)&Gsh[rr][c0] = *(bf16x8*)&h8[0];
  *(bf16x8*)&Gsh[rr][c0 + 8] = *(bf16x8*)&h8[8];
  *(bf16x8*)&Gsl[rr][c0] = *(bf16x8*)&l8[0];
  *(bf16x8*)&Gsl[rr][c0 + 8] = *(bf16x8*)&l8[8];
  __syncthreads();
  // ---- phase B: 4 independent W2 tiles per wave (mt = i*4 + wave) ----
  const int m = lane & 15, q = lane >> 4;
  f32x4 acc[4] = {};
#pragma unroll
  for (int ks = 0; ks < 8; ++ks) {
    const int k = ks * 32 + q * 8;
    const bf16x8 bh = *(const bf16x8*)&Gsh[m][k];
    const bf16x8 bl = *(const bf16x8*)&Gsl[m][k];
#pragma unroll
    for (int i = 0; i < 4; ++i) {
      const int mt = i * 4 + wave;
      const bf16x8 ah = *(const bf16x8*)(Wghi + (size_t)(mt * 16 + m) * 256 + k);
      const bf16x8 al = *(const bf16x8*)(Wglo + (size_t)(mt * 16 + m) * 256 + k);
      acc[i] = __builtin_amdgcn_mfma_f32_16x16x32_bf16(ah, bh, acc[i], 0, 0, 0);
      acc[i] = __builtin_amdgcn_mfma_f32_16x16x32_bf16(ah, bl, acc[i], 0, 0, 0);
      acc[i] = __builtin_amdgcn_mfma_f32_16x16x32_bf16(al, bh, acc[i], 0, 0, 0);
    }
  }
#pragma unroll
  for (int i = 0; i < 4; ++i) {
    const int mt = i * 4 + wave;
#pragma unroll
    for (int r = 0; r < 4; ++r) {
      const size_t off = ((size_t)b << 16) + (size_t)(mt * 16 + q * 4 + r) * 256 +
                         nt * 16 + m;
      const float v = acc[i][r];
      const __bf16 h = (__bf16)v;
      W2hi[off] = h;
      W2lo[off] = (__bf16)(v - (float)h);
    }
  }
}

// ===== k3: W_out (blocks 0..63, 4 tiles/wave) + bias chain (64..79) =============
__global__ __launch_bounds__(256) void wout_mfma_kernel(
    const __bf16* __restrict__ W2hi, const __bf16* __restrict__ W2lo,
    const __bf16* __restrict__ PTthi, const __bf16* __restrict__ PTtlo,
    const float* __restrict__ Wgs, const float* __restrict__ sPT,
    const float* __restrict__ wgb, const float* __restrict__ vpt,
    const float* __restrict__ Wg, const float* __restrict__ t2_g,
    const float* __restrict__ dvec,
    const float* __restrict__ bn_gamma, const float* __restrict__ bn_beta,
    const float* __restrict__ bn_mean, const float* __restrict__ bn_var,
    __bf16* __restrict__ Whi, __bf16* __restrict__ Wlo,
    float* __restrict__ bias_out) {
  const int blk = blockIdx.x;
  const int t = threadIdx.x;
  const int wave = t >> 6, lane = t & 63;
  if (blk < 64) {
    const int batch = blk >> 4, nt = blk & 15;
    const int m = lane & 15, q = lane >> 4;
    const __bf16* bh_p = PTthi + (size_t)(nt * 16 + m) * 256;   // PTt row = PT column
    const __bf16* bl_p = PTtlo + (size_t)(nt * 16 + m) * 256;
    const __bf16* w2h = W2hi + (size_t)batch * 65536;
    const __bf16* w2l = W2lo + (size_t)batch * 65536;
    f32x4 acc[4] = {};
#pragma unroll
    for (int ks = 0; ks < 8; ++ks) {
      const int k = ks * 32 + q * 8;
      const bf16x8 bh = *(const bf16x8*)(bh_p + k);
      const bf16x8 bl = *(const bf16x8*)(bl_p + k);
#pragma unroll
      for (int i = 0; i < 4; ++i) {
        const int mt = i * 4 + wave;
        const bf16x8 ah = *(const bf16x8*)(w2h + (size_t)(mt * 16 + m) * 256 + k);
        const bf16x8 al = *(const bf16x8*)(w2l + (size_t)(mt * 16 + m) * 256 + k);
        acc[i] = __builtin_amdgcn_mfma_f32_16x16x32_bf16(ah, bh, acc[i], 0, 0, 0);
        acc[i] = __builtin_amdgcn_mfma_f32_16x16x32_bf16(ah, bl, acc[i], 0, 0, 0);
        acc[i] = __builtin_amdgcn_mfma_f32_16x16x32_bf16(al, bh, acc[i], 0, 0, 0);
      }
    }
    const float invN = 1.0f / 4096.0f;
    const int c = nt * 16 + m;
    const float vpt_c = vpt[c];
    const float sPT_c = sPT[batch * 256 + c];
#pragma unroll
    for (int i = 0; i < 4; ++i) {
      const int mt = i * 4 + wave;
#pragma unroll
      for (int r = 0; r < 4; ++r) {
        const int o = mt * 16 + q * 4 + r;
        const float sc = bn_gamma[o] * rsqrtf(bn_var[o] + BN_EPS);
        const float w = sc * ((acc[i][r] + Wgs[batch * 256 + o] * vpt_c + wgb[o] * sPT_c) * invN +
                              wgb[o] * vpt_c);
        const size_t off = (size_t)batch * 65536 + (size_t)o * 256 + c;
        const __bf16 h = (__bf16)w;
        Whi[off] = h;
        Wlo[off] = (__bf16)(w - (float)h);
      }
    }
  } else {
    // ---- bias chain: bias = sc*((Wg@t2 + Wgs*d1 + wgb*(d2+N*d1))/N - mean)+beta
    const int p = blk - 64;
    const int b = p >> 2, quarter = p & 3;
    __shared__ float t2s[256];
    t2s[t] = t2_g[b * 256 + t];
    __syncthreads();
    const float d1 = dvec[0], d2 = dvec[1 + b];
    const float invN = 1.0f / 4096.0f;
    const float4 tv = *(const float4*)&t2s[lane * 4];
    for (int it = 0; it < 16; ++it) {
      const int o = quarter * 64 + wave * 16 + it;
      const float4 r = *(const float4*)(Wg + (size_t)o * 256 + lane * 4);
      float v = fmaf(r.x, tv.x, fmaf(r.y, tv.y, fmaf(r.z, tv.z, r.w * tv.w)));
      v = wave_reduce(v);
      if (lane == 0) {
        const float bias_full = (v + Wgs[b * 256 + o] * d1 +
                                 wgb[o] * (d2 + 4096.0f * d1)) * invN;
        const float sc = bn_gamma[o] * rsqrtf(bn_var[o] + BN_EPS);
        bias_out[b * 256 + o] = sc * (bias_full - bn_mean[o]) + bn_beta[o];
      }
    }
  }
}

// ===== k4: out[b] = W_out[b] @ a[b] + bias — register-resident W ================
__global__ __launch_bounds__(256) void out_mfma_kernel(const __bf16* __restrict__ Whi,
                                                       const __bf16* __restrict__ Wlo,
                                                       const __bf16* __restrict__ at,
                                                       const float* __restrict__ bias_out,
                                                       float* __restrict__ out) {
  const int ng = blockIdx.x, mt = blockIdx.y, b = blockIdx.z;
  const int wave = threadIdx.x >> 6, lane = threadIdx.x & 63;
  const int m = lane & 15, q = lane >> 4;
  const int o = mt * 64 + wave * 16 + m;
  const __bf16* wh = Whi + (size_t)b * 65536 + (size_t)o * 256;
  const __bf16* wl = Wlo + (size_t)b * 65536 + (size_t)o * 256;
  bf16x8 ah[8], al[8];
#pragma unroll
  for (int ks = 0; ks < 8; ++ks) {
    ah[ks] = *(const bf16x8*)(wh + ks * 32 + q * 8);
    al[ks] = *(const bf16x8*)(wl + ks * 32 + q * 8);
  }
  float bo[4];
#pragma unroll
  for (int r = 0; r < 4; ++r)
    bo[r] = bias_out[b * 256 + mt * 64 + wave * 16 + q * 4 + r];
  float* ob = out + (size_t)b * CCH * NSP;
#pragma unroll
  for (int nt4 = 0; nt4 < 2; ++nt4) {
    const __bf16* atb = at + ((size_t)b * NSP + ng * 128 + nt4 * 64) * CCH;
    f32x4 acc[4] = {};
#pragma unroll
    for (int ks = 0; ks < 8; ++ks) {
      const int k = ks * 32 + q * 8;
#pragma unroll
      for (int t4 = 0; t4 < 4; ++t4) {
        const bf16x8 bh = *(const bf16x8*)(atb + (size_t)(t4 * 16 + m) * 256 + k);
        acc[t4] = __builtin_amdgcn_mfma_f32_16x16x32_bf16(ah[ks], bh, acc[t4], 0, 0, 0);
        acc[t4] = __builtin_amdgcn_mfma_f32_16x16x32_bf16(al[ks], bh, acc[t4], 0, 0, 0);
      }
    }
#pragma unroll
    for (int r = 0; r < 4; ++r) {
      const int orow = mt * 64 + wave * 16 + q * 4 + r;
#pragma unroll
      for (int t4 = 0; t4 < 4; ++t4)
        ob[(size_t)orow * NSP + ng * 128 + nt4 * 64 + t4 * 16 + m] = acc[t4][r] + bo[r];
    }
  }
}

extern "C" void kernel_launch(void* const* d_in, const int* in_sizes, int n_in,
                              void* d_out, int out_size, void* d_ws, size_t ws_size,
                              hipStream_t stream) {
  (void)in_sizes; (void)n_in; (void)out_size; (void)ws_size;
  const float* a       = (const float*)d_in[0];
  const float* bI      = (const float*)d_in[1];
  const float* theta_w = (const float*)d_in[2];
  const float* theta_b = (const float*)d_in[3];
  const float* phi_w   = (const float*)d_in[4];
  const float* phi_b   = (const float*)d_in[5];
  const float* g_w     = (const float*)d_in[6];
  const float* g_b     = (const float*)d_in[7];
  const float* W_w     = (const float*)d_in[8];
  const float* bn_gamma= (const float*)d_in[9];
  const float* bn_beta = (const float*)d_in[10];
  const float* bn_mean = (const float*)d_in[11];
  const float* bn_var  = (const float*)d_in[12];
  float* out = (float*)d_out;
  float* ws  = (float*)d_ws;

  // fp32 region (float offsets)
  float* Gpart    = ws;                  // 8 MB used (kc-split 8)
  float* srow     = ws + 4194304;        // 1024
  float* Wg       = ws + 4195328;        // 65536
  float* bias_out = ws + 4260864;        // 1024
  float* Wgs      = ws + 4261888;        // 1024
  float* sPTv     = ws + 4262912;        // 1024
  float* wgb      = ws + 4263936;        // 256
  float* vpt      = ws + 4264192;        // 256
  float* vb_g     = ws + 4264448;        // 256
  float* t2_g     = ws + 4264704;        // 1024
  float* dvec     = ws + 4265728;        // 8 (pad to 256)
  // bf16 region
  __bf16* at    = (__bf16*)(ws + 4265984);   // 8 MB
  __bf16* Wghi  = (__bf16*)(ws + 6363136);   // 128 KB each below
  __bf16* Wglo  = (__bf16*)(ws + 6395904);
  __bf16* PTthi = (__bf16*)(ws + 6428672);
  __bf16* PTtlo = (__bf16*)(ws + 6461440);
  __bf16* W2hi  = (__bf16*)(ws + 6494208);   // 512 KB each below
  __bf16* W2lo  = (__bf16*)(ws + 6625280);
  __bf16* Whi   = (__bf16*)(ws + 6756352);
  __bf16* Wlo   = (__bf16*)(ws + 6887424);
  __bf16* bhi   = (__bf16*)(ws + 7018496);   // 8 MB
  __bf16* blo   = (__bf16*)(ws + 9115648);   // 8 MB, end ~44.9 MB

  prep_kernel<<<dim3(2086), dim3(256), 0, stream>>>(bI, a, W_w, g_w, phi_w, theta_w,
                                                    phi_b, theta_b, g_b,
                                                    bhi, blo, srow, Wg, Wghi, Wglo,
                                                    PTthi, PTtlo, at,
                                                    vb_g, vpt, wgb, dvec);
  gram_kernel<<<dim3(384), dim3(256), 0, stream>>>(bhi, blo, Gpart, srow, Wg,
                                                   PTthi, PTtlo, vb_g,
                                                   Wgs, sPTv, dvec);
  redw2_kernel<<<dim3(64), dim3(256), 0, stream>>>(Gpart, vb_g, t2_g,
                                                   Wghi, Wglo, W2hi, W2lo);
  wout_mfma_kernel<<<dim3(80), dim3(256), 0, stream>>>(W2hi, W2lo, PTthi, PTtlo,
                                                       Wgs, sPTv, wgb, vpt, Wg, t2_g,
                                                       dvec, bn_gamma, bn_beta, bn_mean,
                                                       bn_var, Whi, Wlo, bias_out);
  out_mfma_kernel<<<dim3(32, 4, 4), dim3(256), 0, stream>>>(Whi, Wlo, at, bias_out, out);
}

// Round 7
// 165.082 us; speedup vs baseline: 1.2331x; 1.0324x over previous
//
#include <hip/hip_runtime.h>
#include <hip/hip_bf16.h>

#define NSP 4096   // H*W
#define CCH 256    // C
#define CIN 128    // Ci
#define BN_EPS 1e-5f

typedef __bf16 bf16x8 __attribute__((ext_vector_type(8)));
typedef __bf16 bf16x4 __attribute__((ext_vector_type(4)));
typedef float f32x4 __attribute__((ext_vector_type(4)));
typedef unsigned short u16x8 __attribute__((ext_vector_type(8)));

typedef const __attribute__((address_space(1))) unsigned int gu32;
typedef __attribute__((address_space(3))) unsigned int lu32;

// upper-triangle tile enumeration for the symmetric Gram (10 of 16 tiles)
__constant__ int IT10[10] = {0,0,0,0,1,1,1,2,2,3};
__constant__ int JT10[10] = {0,1,2,3,1,2,3,2,3,3};

// ================= fp32 tile helpers (weight prep only) ==========================

__device__ __forceinline__ float4 fetch_tr(const float* __restrict__ A, int lda, int m0,
                                           int k0, int tid) {
  const int r = tid >> 2, kq = (tid & 3) << 2;
  return *(const float4*)(A + (size_t)(m0 + r) * lda + k0 + kq);
}
__device__ __forceinline__ void stash_tr(float (*As)[68], float4 v, int tid) {
  const int r = tid >> 2, kq = (tid & 3) << 2;
  As[kq + 0][r] = v.x; As[kq + 1][r] = v.y; As[kq + 2][r] = v.z; As[kq + 3][r] = v.w;
}
__device__ __forceinline__ float4 fetch_dir(const float* __restrict__ B, int ldb, int k0,
                                            int n0, int tid) {
  const int kr = tid >> 4, nq = (tid & 15) << 2;
  return *(const float4*)(B + (size_t)(k0 + kr) * ldb + n0 + nq);
}
__device__ __forceinline__ void stash_dir(float (*Bs)[68], float4 v, int tid) {
  const int kr = tid >> 4, nq = (tid & 15) << 2;
  *(float4*)(&Bs[kr][nq]) = v;
}

__device__ __forceinline__ void mm16(const float (*As)[68], const float (*Bs)[68],
                                     float acc[4][4], int ty, int tx) {
#pragma unroll
  for (int kk = 0; kk < 16; ++kk) {
    const float4 av = *(const float4*)(&As[kk][ty << 2]);
    const float4 bv = *(const float4*)(&Bs[kk][tx << 2]);
    const float ar[4] = {av.x, av.y, av.z, av.w};
    const float br[4] = {bv.x, bv.y, bv.z, bv.w};
#pragma unroll
    for (int i = 0; i < 4; ++i)
#pragma unroll
      for (int j = 0; j < 4; ++j) acc[i][j] += ar[i] * br[j];
  }
}

__device__ __forceinline__ float wave_reduce(float v) {
#pragma unroll
  for (int off = 32; off; off >>= 1) v += __shfl_down(v, off);
  return v;  // valid in lane 0
}

// ===== k0: cast_b + srow ONLY (the sole gram dependency) ========================
__global__ __launch_bounds__(256) void castb_kernel(
    const float* __restrict__ bin,
    __bf16* __restrict__ bhi, __bf16* __restrict__ blo,
    float* __restrict__ srow) {
  __shared__ float smem[4];
  const int t = threadIdx.x;
  const int wave = t >> 6, lane = t & 63;
  const int row = blockIdx.x;  // global row over 4*256
  const float* src = bin + (size_t)row * NSP + t * 16;
  float sum = 0.f;
  unsigned short h16[16], l16[16];
#pragma unroll
  for (int i = 0; i < 4; ++i) {
    const float4 v = *(const float4*)(src + i * 4);
    const float vv[4] = {v.x, v.y, v.z, v.w};
    sum += v.x + v.y + v.z + v.w;
#pragma unroll
    for (int e = 0; e < 4; ++e) {
      const unsigned u = __float_as_uint(vv[e]);
      h16[i * 4 + e] = (unsigned short)(u >> 16);
      const float hf = __uint_as_float(u & 0xffff0000u);
      l16[i * 4 + e] = (unsigned short)(__float_as_uint(vv[e] - hf) >> 16);
    }
  }
  unsigned short* dh = (unsigned short*)bhi + (size_t)row * NSP + t * 16;
  unsigned short* dl = (unsigned short*)blo + (size_t)row * NSP + t * 16;
  *(u16x8*)dh = *(u16x8*)&h16[0];
  *(u16x8*)(dh + 8) = *(u16x8*)&h16[8];
  *(u16x8*)dl = *(u16x8*)&l16[0];
  *(u16x8*)(dl + 8) = *(u16x8*)&l16[8];
#pragma unroll
  for (int off = 32; off; off >>= 1) sum += __shfl_down(sum, off);
  if (lane == 0) smem[wave] = sum;
  __syncthreads();
  if (t == 0) srow[row] = smem[0] + smem[1] + smem[2] + smem[3];
}

// ===== k1: gram (0..319) ∪ cast_a (320..1343) ∪ wprep (1344..1375) ∪ small (1376..1381)
// All branches mutually independent; gram depends only on k0 (bhi/blo). Gram
// keeps blockIdx 0..319 so kc = idx&7 pins each (kc,batch) group to one XCD.
__global__ __launch_bounds__(256) void gram_plus_kernel(
    const __bf16* __restrict__ bhi, const __bf16* __restrict__ blo,
    float* __restrict__ Gpart,
    const float* __restrict__ a,
    const float* __restrict__ W_w, const float* __restrict__ g_w,
    const float* __restrict__ phi_w, const float* __restrict__ theta_w,
    const float* __restrict__ phi_b, const float* __restrict__ theta_b,
    const float* __restrict__ g_b,
    float* __restrict__ Wg, __bf16* __restrict__ Wghi, __bf16* __restrict__ Wglo,
    __bf16* __restrict__ PTthi, __bf16* __restrict__ PTtlo,
    __bf16* __restrict__ at,
    float* __restrict__ vb_g, float* __restrict__ vpt, float* __restrict__ wgb,
    float* __restrict__ dvec) {
  __shared__ __align__(16) __bf16 AtBt[2][2][64][64];   // 32 KB, aliased by branches
  auto& At = AtBt[0];
  auto& Bt = AtBt[1];
  float* smem = (float*)AtBt;
  const int idx = blockIdx.x;
  const int t = threadIdx.x;
  const int wave = t >> 6, lane = t & 63;
  if (idx < 320) {
    // ---- gram: symmetric upper-triangle, LDS-staged bf16 MFMA ----
    const int kc = idx & 7;            // XCD id
    const int rest = idx >> 3;         // 0..39
    const int tile = rest % 10;
    const int batch = rest / 10;       // 0..3
    const int it = IT10[tile], jt = JT10[tile];
    const bool diag = (it == jt);
    const int m = lane & 15, q = lane >> 4;
    const size_t rowbase = (size_t)batch * CCH;
    const int colbase = kc * 512;
    const int rseg = lane >> 3, ch = lane & 7;
    const int u = ch ^ rseg;          // r&7 == rseg since segments are 8-row aligned
    const int h = u >> 2, j = u & 3;
    const __bf16* gsrc = h ? blo : bhi;

    auto stage = [&](int ph, int ks) {
#pragma unroll
      for (int c = 0; c < 4; ++c) {
        const int s = wave * 4 + c;     // 0..15: 0-7 A-tile KBs, 8-15 B-tile KBs
        const int isB = s >> 3;
        if (diag && isB) continue;      // block-uniform: diag reads A twice
        const int kb = s & 7;
        const int grow = (isB ? jt : it) * 64 + kb * 8 + rseg;
        const __bf16* gp = gsrc + (rowbase + (size_t)grow) * NSP +
                           colbase + ks * 32 + j * 8;
        const __bf16* lp = isB ? &Bt[ph][kb * 8][0] : &At[ph][kb * 8][0];
        __builtin_amdgcn_global_load_lds((gu32*)(const void*)gp,
                                         (lu32*)(void*)lp, 16, 0, 0);
      }
    };

    f32x4 acc[4] = {};
    const int chA = q ^ (m & 7);      // hi chunk for this lane's rows (r&7 == m&7)
    stage(0, 0);
    int ph = 0;
    for (int ks = 0; ks < 16; ++ks) {
      __syncthreads();                // stage(ks) visible (vmcnt drained at barrier)
      if (ks < 15) stage(ph ^ 1, ks + 1);
      const bf16x8 ah = *(const bf16x8*)&At[ph][wave * 16 + m][chA * 8];
      const bf16x8 al = *(const bf16x8*)&At[ph][wave * 16 + m][(chA ^ 4) * 8];
      const __bf16 (*Bsrc)[64] = diag ? At[ph] : Bt[ph];
#pragma unroll
      for (int t4 = 0; t4 < 4; ++t4) {
        const bf16x8 bh = *(const bf16x8*)&Bsrc[t4 * 16 + m][chA * 8];
        const bf16x8 bl = *(const bf16x8*)&Bsrc[t4 * 16 + m][(chA ^ 4) * 8];
        acc[t4] = __builtin_amdgcn_mfma_f32_16x16x32_bf16(ah, bh, acc[t4], 0, 0, 0);
        acc[t4] = __builtin_amdgcn_mfma_f32_16x16x32_bf16(ah, bl, acc[t4], 0, 0, 0);
        acc[t4] = __builtin_amdgcn_mfma_f32_16x16x32_bf16(al, bh, acc[t4], 0, 0, 0);
      }
      ph ^= 1;
    }
    float* Gp = Gpart + ((size_t)(kc * 4 + batch)) * 65536;
#pragma unroll
    for (int t4 = 0; t4 < 4; ++t4)
#pragma unroll
      for (int r = 0; r < 4; ++r)
        Gp[(size_t)(it * 64 + wave * 16 + q * 4 + r) * 256 + jt * 64 + t4 * 16 + m] =
            acc[t4][r];
    if (!diag) {
      // mirror: G[jt-tile][it-tile] = transpose, via LDS (coalesced global write)
      __syncthreads();                          // all MFMA reads of AtBt done
      float* Tf = (float*)AtBt;                 // [64][68] fp32, 17.4 KB
#pragma unroll
      for (int t4 = 0; t4 < 4; ++t4)
#pragma unroll
        for (int r = 0; r < 4; ++r)
          Tf[(t4 * 16 + m) * 68 + wave * 16 + q * 4 + r] = acc[t4][r];
      __syncthreads();
      const int rr = t >> 2, cq = (t & 3) * 16;
      float* Gpt = Gp + (size_t)(jt * 64 + rr) * 256 + it * 64 + cq;
#pragma unroll
      for (int i = 0; i < 4; ++i)
        *(float4*)(Gpt + i * 4) = *(const float4*)&Tf[rr * 68 + cq + i * 4];
    }
  } else if (idx < 1344) {
    // ---- cast a -> bf16 transposed: at[b][n][c] ----
    const int p = idx - 320;
    const int n0 = (p & 63) * 64, c0 = ((p >> 6) & 3) * 64, b = p >> 8;
    float (*tile)[68] = (float(*)[68])smem;
    const int cr = t >> 4, nq = (t & 15) << 2;
    const float* src = a + ((size_t)(b * CCH + c0)) * NSP + n0;
#pragma unroll
    for (int s = 0; s < 4; ++s) {
      const float4 v = *(const float4*)(src + (size_t)(cr + s * 16) * NSP + nq);
      *(float4*)&tile[cr + s * 16][nq] = v;
    }
    __syncthreads();
    const int n = t >> 2, cq = (t & 3) << 4;
    __bf16 outv[16];
#pragma unroll
    for (int i = 0; i < 16; ++i) outv[i] = (__bf16)tile[cq + i][n];
    __bf16* dst = at + ((size_t)(b * NSP + n0 + n)) * CCH + c0 + cq;
    *(bf16x8*)dst = *(bf16x8*)&outv[0];
    *(bf16x8*)(dst + 8) = *(bf16x8*)&outv[8];
  } else if (idx < 1376) {
    // ---- wprep: Wg = W_w @ g_w (z=0) ; PTt = theta_w^T @ phi_w (z=1) ----
    const int p = idx - 1344;
    const int zsel = p >> 4, rem = p & 15;
    const int m0 = (rem >> 2) * 64, n0 = (rem & 3) * 64;
    float (*As)[68] = (float(*)[68])smem;
    float (*Bs)[68] = (float(*)[68])(smem + 16 * 68);
    const int ty = t >> 4, tx = t & 15;
    float acc[4][4] = {};
    if (zsel == 0) {
      float4 ar = fetch_tr(W_w, CIN, m0, 0, t);
      float4 br = fetch_dir(g_w, CCH, 0, n0, t);
      for (int kt = 0; kt < 8; ++kt) {
        stash_tr(As, ar, t); stash_dir(Bs, br, t);
        __syncthreads();
        if (kt < 7) { ar = fetch_tr(W_w, CIN, m0, (kt + 1) * 16, t);
                      br = fetch_dir(g_w, CCH, (kt + 1) * 16, n0, t); }
        mm16(As, Bs, acc, ty, tx);
        __syncthreads();
      }
#pragma unroll
      for (int i = 0; i < 4; ++i) {
        const size_t off = (size_t)(m0 + (ty << 2) + i) * 256 + n0 + (tx << 2);
        *(float4*)(Wg + off) = make_float4(acc[i][0], acc[i][1], acc[i][2], acc[i][3]);
        __bf16 h4[4], l4[4];
#pragma unroll
        for (int j = 0; j < 4; ++j) {
          const __bf16 h = (__bf16)acc[i][j];
          h4[j] = h; l4[j] = (__bf16)(acc[i][j] - (float)h);
        }
        *(bf16x4*)(Wghi + off) = *(bf16x4*)h4;
        *(bf16x4*)(Wglo + off) = *(bf16x4*)l4;
      }
    } else {
      float4 ar = fetch_dir(theta_w, CCH, 0, m0, t);   // swapped: computes PT^T
      float4 br = fetch_dir(phi_w, CCH, 0, n0, t);
      for (int kt = 0; kt < 8; ++kt) {
        stash_dir(As, ar, t); stash_dir(Bs, br, t);
        __syncthreads();
        if (kt < 7) { ar = fetch_dir(theta_w, CCH, (kt + 1) * 16, m0, t);
                      br = fetch_dir(phi_w, CCH, (kt + 1) * 16, n0, t); }
        mm16(As, Bs, acc, ty, tx);
        __syncthreads();
      }
#pragma unroll
      for (int i = 0; i < 4; ++i) {
        const size_t off = (size_t)(m0 + (ty << 2) + i) * 256 + n0 + (tx << 2);
        __bf16 h4[4], l4[4];
#pragma unroll
        for (int j = 0; j < 4; ++j) {
          const __bf16 h = (__bf16)acc[i][j];
          h4[j] = h; l4[j] = (__bf16)(acc[i][j] - (float)h);
        }
        *(bf16x4*)(PTthi + off) = *(bf16x4*)h4;
        *(bf16x4*)(PTtlo + off) = *(bf16x4*)l4;
      }
    }
  } else if (idx == 1376) {
    // ---- vb[c] = phi_w^T @ theta_b ; d1 = phi_b . theta_b ----
    float* tb_s = smem;
    float* pb_s = smem + 128;
    if (t < 128) { tb_s[t] = theta_b[t]; pb_s[t] = phi_b[t]; }
    __syncthreads();
    float acc = 0.f;
#pragma unroll 8
    for (int i = 0; i < 128; ++i) acc += phi_w[(size_t)i * 256 + t] * tb_s[i];
    vb_g[t] = acc;
    if (t < 64) {
      float pv = pb_s[t] * tb_s[t] + pb_s[t + 64] * tb_s[t + 64];
      pv = wave_reduce(pv);
      if (t == 0) dvec[0] = pv;
    }
  } else if (idx == 1377) {
    // ---- vpt[c] = phi_b^T @ theta_w ----
    float* pb_s = smem;
    if (t < 128) pb_s[t] = phi_b[t];
    __syncthreads();
    float acc = 0.f;
#pragma unroll 8
    for (int i = 0; i < 128; ++i) acc += pb_s[i] * theta_w[(size_t)i * 256 + t];
    vpt[t] = acc;
  } else {
    // ---- wgb[o] = W_w[o] . g_b : 4 blocks x 64 outputs ----
    const int p = idx - 1378;
    float* gb_s = smem;
    if (t < 128) gb_s[t] = g_b[t];
    __syncthreads();
    const float2 gv = *(const float2*)&gb_s[lane * 2];
    for (int i = 0; i < 16; ++i) {
      const int o = p * 64 + wave * 16 + i;
      const float2 r = *(const float2*)(W_w + (size_t)o * 128 + lane * 2);
      float v = fmaf(r.x, gv.x, r.y * gv.y);
      v = wave_reduce(v);
      if (lane == 0) wgb[o] = v;
    }
  }
}

// ===== k2: fused reduce+W2 (0..63) + aux Wgs/sPTv/d2 (64..127) ==================
__global__ __launch_bounds__(256) void redw2_kernel(
    const float* __restrict__ Gpart, const float* __restrict__ vb_g,
    float* __restrict__ t2_g, const float* __restrict__ srow,
    const float* __restrict__ Wg,
    const __bf16* __restrict__ Wghi, const __bf16* __restrict__ Wglo,
    const __bf16* __restrict__ PTthi, const __bf16* __restrict__ PTtlo,
    __bf16* __restrict__ W2hi, __bf16* __restrict__ W2lo,
    float* __restrict__ Wgs, float* __restrict__ sPTv, float* __restrict__ dvec) {
  const int blk = blockIdx.x;
  const int t = threadIdx.x;
  const int wave = t >> 6, lane = t & 63;
  __shared__ __bf16 Gsh[16][264], Gsl[16][264];   // +8 pad: 2-way banks only
  __shared__ float lds[256];
  if (blk < 64) {
    const int b = blk >> 4, nt = blk & 15;
    // ---- phase A: reduce 16 rows x 256 cols over 8 partials (read once) ----
    const int rr = t >> 4;
    const int c0 = (t & 15) * 16;
    f32x4 s[4] = {};
#pragma unroll
    for (int p = 0; p < 8; ++p) {
      const float* src = Gpart + (((size_t)(p * 4 + b)) << 16) +
                         (size_t)(nt * 16 + rr) * 256 + c0;
#pragma unroll
      for (int e = 0; e < 4; ++e) s[e] += *(const f32x4*)(src + e * 4);
    }
    {
      float part = 0.f;
#pragma unroll
      for (int e = 0; e < 4; ++e) {
        const float4 vv = *(const float4*)(vb_g + c0 + e * 4);
        part += s[e][0] * vv.x + s[e][1] * vv.y + s[e][2] * vv.z + s[e][3] * vv.w;
      }
#pragma unroll
      for (int off = 8; off; off >>= 1) part += __shfl_down(part, off);
      if ((t & 15) == 0) t2_g[b * 256 + nt * 16 + rr] = part;
    }
    __bf16 h8[16], l8[16];
#pragma unroll
    for (int e = 0; e < 16; ++e) {
      const float x = s[e >> 2][e & 3];
      const __bf16 h = (__bf16)x;
      h8[e] = h; l8[e] = (__bf16)(x - (float)h);
    }
    *(bf16x8*)&Gsh[rr][c0] = *(bf16x8*)&h8[0];
    *(bf16x8*)&Gsh[rr][c0 + 8] = *(bf16x8*)&h8[8];
    *(bf16x8*)&Gsl[rr][c0] = *(bf16x8*)&l8[0];
    *(bf16x8*)&Gsl[rr][c0 + 8] = *(bf16x8*)&l8[8];
    __syncthreads();
    // ---- phase B: 4 independent W2 tiles per wave (mt = i*4 + wave) ----
    const int m = lane & 15, q = lane >> 4;
    f32x4 acc[4] = {};
#pragma unroll
    for (int ks = 0; ks < 8; ++ks) {
      const int k = ks * 32 + q * 8;
      const bf16x8 bh = *(const bf16x8*)&Gsh[m][k];
      const bf16x8 bl = *(const bf16x8*)&Gsl[m][k];
#pragma unroll
      for (int i = 0; i < 4; ++i) {
        const int mt = i * 4 + wave;
        const bf16x8 ah = *(const bf16x8*)(Wghi + (size_t)(mt * 16 + m) * 256 + k);
        const bf16x8 al = *(const bf16x8*)(Wglo + (size_t)(mt * 16 + m) * 256 + k);
        acc[i] = __builtin_amdgcn_mfma_f32_16x16x32_bf16(ah, bh, acc[i], 0, 0, 0);
        acc[i] = __builtin_amdgcn_mfma_f32_16x16x32_bf16(ah, bl, acc[i], 0, 0, 0);
        acc[i] = __builtin_amdgcn_mfma_f32_16x16x32_bf16(al, bh, acc[i], 0, 0, 0);
      }
    }
#pragma unroll
    for (int i = 0; i < 4; ++i) {
      const int mt = i * 4 + wave;
#pragma unroll
      for (int r = 0; r < 4; ++r) {
        const size_t off = ((size_t)b << 16) + (size_t)(mt * 16 + q * 4 + r) * 256 +
                           nt * 16 + m;
        const float v = acc[i][r];
        const __bf16 h = (__bf16)v;
        W2hi[off] = h;
        W2lo[off] = (__bf16)(v - (float)h);
      }
    }
  } else {
    // ---- aux: Wgs = Wg@s ; sPTv = PTt@s ; d2 = s.vb ----
    const int p = blk - 64;
    const int b = p >> 4, seg = p & 15;
    lds[t] = srow[b * 256 + t];
    __syncthreads();
    const float4 sv = *(const float4*)&lds[lane * 4];
    for (int i = wave; i < 16; i += 4) {
      const int o = seg * 16 + i;
      const float4 r = *(const float4*)(Wg + (size_t)o * 256 + lane * 4);
      float v = fmaf(r.x, sv.x, fmaf(r.y, sv.y, fmaf(r.z, sv.z, r.w * sv.w)));
      v = wave_reduce(v);
      if (lane == 0) Wgs[b * 256 + o] = v;
    }
    for (int i = wave; i < 16; i += 4) {
      const int c = seg * 16 + i;
      const bf16x4 ph = *(const bf16x4*)(PTthi + (size_t)c * 256 + lane * 4);
      const bf16x4 pl = *(const bf16x4*)(PTtlo + (size_t)c * 256 + lane * 4);
      const float svv[4] = {sv.x, sv.y, sv.z, sv.w};
      float v = 0.f;
#pragma unroll
      for (int e = 0; e < 4; ++e) v += ((float)ph[e] + (float)pl[e]) * svv[e];
      v = wave_reduce(v);
      if (lane == 0) sPTv[b * 256 + c] = v;
    }
    if (seg == 0 && wave == 0) {
      const float4 vbv = *(const float4*)(vb_g + lane * 4);
      float v = fmaf(vbv.x, sv.x, fmaf(vbv.y, sv.y, fmaf(vbv.z, sv.z, vbv.w * sv.w)));
      v = wave_reduce(v);
      if (lane == 0) dvec[1 + b] = v;
    }
  }
}

// ===== k3: W_out (blocks 0..63, 4 tiles/wave) + bias chain (64..79) =============
__global__ __launch_bounds__(256) void wout_mfma_kernel(
    const __bf16* __restrict__ W2hi, const __bf16* __restrict__ W2lo,
    const __bf16* __restrict__ PTthi, const __bf16* __restrict__ PTtlo,
    const float* __restrict__ Wgs, const float* __restrict__ sPT,
    const float* __restrict__ wgb, const float* __restrict__ vpt,
    const float* __restrict__ Wg, const float* __restrict__ t2_g,
    const float* __restrict__ dvec,
    const float* __restrict__ bn_gamma, const float* __restrict__ bn_beta,
    const float* __restrict__ bn_mean, const float* __restrict__ bn_var,
    __bf16* __restrict__ Whi, __bf16* __restrict__ Wlo,
    float* __restrict__ bias_out) {
  const int blk = blockIdx.x;
  const int t = threadIdx.x;
  const int wave = t >> 6, lane = t & 63;
  if (blk < 64) {
    const int batch = blk >> 4, nt = blk & 15;
    const int m = lane & 15, q = lane >> 4;
    const __bf16* bh_p = PTthi + (size_t)(nt * 16 + m) * 256;   // PTt row = PT column
    const __bf16* bl_p = PTtlo + (size_t)(nt * 16 + m) * 256;
    const __bf16* w2h = W2hi + (size_t)batch * 65536;
    const __bf16* w2l = W2lo + (size_t)batch * 65536;
    f32x4 acc[4] = {};
#pragma unroll
    for (int ks = 0; ks < 8; ++ks) {
      const int k = ks * 32 + q * 8;
      const bf16x8 bh = *(const bf16x8*)(bh_p + k);
      const bf16x8 bl = *(const bf16x8*)(bl_p + k);
#pragma unroll
      for (int i = 0; i < 4; ++i) {
        const int mt = i * 4 + wave;
        const bf16x8 ah = *(const bf16x8*)(w2h + (size_t)(mt * 16 + m) * 256 + k);
        const bf16x8 al = *(const bf16x8*)(w2l + (size_t)(mt * 16 + m) * 256 + k);
        acc[i] = __builtin_amdgcn_mfma_f32_16x16x32_bf16(ah, bh, acc[i], 0, 0, 0);
        acc[i] = __builtin_amdgcn_mfma_f32_16x16x32_bf16(ah, bl, acc[i], 0, 0, 0);
        acc[i] = __builtin_amdgcn_mfma_f32_16x16x32_bf16(al, bh, acc[i], 0, 0, 0);
      }
    }
    const float invN = 1.0f / 4096.0f;
    const int c = nt * 16 + m;
    const float vpt_c = vpt[c];
    const float sPT_c = sPT[batch * 256 + c];
#pragma unroll
    for (int i = 0; i < 4; ++i) {
      const int mt = i * 4 + wave;
#pragma unroll
      for (int r = 0; r < 4; ++r) {
        const int o = mt * 16 + q * 4 + r;
        const float sc = bn_gamma[o] * rsqrtf(bn_var[o] + BN_EPS);
        const float w = sc * ((acc[i][r] + Wgs[batch * 256 + o] * vpt_c + wgb[o] * sPT_c) * invN +
                              wgb[o] * vpt_c);
        const size_t off = (size_t)batch * 65536 + (size_t)o * 256 + c;
        const __bf16 h = (__bf16)w;
        Whi[off] = h;
        Wlo[off] = (__bf16)(w - (float)h);
      }
    }
  } else {
    // ---- bias chain: bias = sc*((Wg@t2 + Wgs*d1 + wgb*(d2+N*d1))/N - mean)+beta
    const int p = blk - 64;
    const int b = p >> 2, quarter = p & 3;
    __shared__ float t2s[256];
    t2s[t] = t2_g[b * 256 + t];
    __syncthreads();
    const float d1 = dvec[0], d2 = dvec[1 + b];
    const float invN = 1.0f / 4096.0f;
    const float4 tv = *(const float4*)&t2s[lane * 4];
    for (int it = 0; it < 16; ++it) {
      const int o = quarter * 64 + wave * 16 + it;
      const float4 r = *(const float4*)(Wg + (size_t)o * 256 + lane * 4);
      float v = fmaf(r.x, tv.x, fmaf(r.y, tv.y, fmaf(r.z, tv.z, r.w * tv.w)));
      v = wave_reduce(v);
      if (lane == 0) {
        const float bias_full = (v + Wgs[b * 256 + o] * d1 +
                                 wgb[o] * (d2 + 4096.0f * d1)) * invN;
        const float sc = bn_gamma[o] * rsqrtf(bn_var[o] + BN_EPS);
        bias_out[b * 256 + o] = sc * (bias_full - bn_mean[o]) + bn_beta[o];
      }
    }
  }
}

// ===== k4: out[b] = W_out[b] @ a[b] + bias — register-resident W ================
__global__ __launch_bounds__(256) void out_mfma_kernel(const __bf16* __restrict__ Whi,
                                                       const __bf16* __restrict__ Wlo,
                                                       const __bf16* __restrict__ at,
                                                       const float* __restrict__ bias_out,
                                                       float* __restrict__ out) {
  const int ng = blockIdx.x, mt = blockIdx.y, b = blockIdx.z;
  const int wave = threadIdx.x >> 6, lane = threadIdx.x & 63;
  const int m = lane & 15, q = lane >> 4;
  const int o = mt * 64 + wave * 16 + m;
  const __bf16* wh = Whi + (size_t)b * 65536 + (size_t)o * 256;
  const __bf16* wl = Wlo + (size_t)b * 65536 + (size_t)o * 256;
  bf16x8 ah[8], al[8];
#pragma unroll
  for (int ks = 0; ks < 8; ++ks) {
    ah[ks] = *(const bf16x8*)(wh + ks * 32 + q * 8);
    al[ks] = *(const bf16x8*)(wl + ks * 32 + q * 8);
  }
  float bo[4];
#pragma unroll
  for (int r = 0; r < 4; ++r)
    bo[r] = bias_out[b * 256 + mt * 64 + wave * 16 + q * 4 + r];
  float* ob = out + (size_t)b * CCH * NSP;
#pragma unroll
  for (int nt4 = 0; nt4 < 2; ++nt4) {
    const __bf16* atb = at + ((size_t)b * NSP + ng * 128 + nt4 * 64) * CCH;
    f32x4 acc[4] = {};
#pragma unroll
    for (int ks = 0; ks < 8; ++ks) {
      const int k = ks * 32 + q * 8;
#pragma unroll
      for (int t4 = 0; t4 < 4; ++t4) {
        const bf16x8 bh = *(const bf16x8*)(atb + (size_t)(t4 * 16 + m) * 256 + k);
        acc[t4] = __builtin_amdgcn_mfma_f32_16x16x32_bf16(ah[ks], bh, acc[t4], 0, 0, 0);
        acc[t4] = __builtin_amdgcn_mfma_f32_16x16x32_bf16(al[ks], bh, acc[t4], 0, 0, 0);
      }
    }
#pragma unroll
    for (int r = 0; r < 4; ++r) {
      const int orow = mt * 64 + wave * 16 + q * 4 + r;
#pragma unroll
      for (int t4 = 0; t4 < 4; ++t4)
        ob[(size_t)orow * NSP + ng * 128 + nt4 * 64 + t4 * 16 + m] = acc[t4][r] + bo[r];
    }
  }
}

extern "C" void kernel_launch(void* const* d_in, const int* in_sizes, int n_in,
                              void* d_out, int out_size, void* d_ws, size_t ws_size,
                              hipStream_t stream) {
  (void)in_sizes; (void)n_in; (void)out_size; (void)ws_size;
  const float* a       = (const float*)d_in[0];
  const float* bI      = (const float*)d_in[1];
  const float* theta_w = (const float*)d_in[2];
  const float* theta_b = (const float*)d_in[3];
  const float* phi_w   = (const float*)d_in[4];
  const float* phi_b   = (const float*)d_in[5];
  const float* g_w     = (const float*)d_in[6];
  const float* g_b     = (const float*)d_in[7];
  const float* W_w     = (const float*)d_in[8];
  const float* bn_gamma= (const float*)d_in[9];
  const float* bn_beta = (const float*)d_in[10];
  const float* bn_mean = (const float*)d_in[11];
  const float* bn_var  = (const float*)d_in[12];
  float* out = (float*)d_out;
  float* ws  = (float*)d_ws;

  // fp32 region (float offsets)
  float* Gpart    = ws;                  // 8 MB used (kc-split 8)
  float* srow     = ws + 4194304;        // 1024
  float* Wg       = ws + 4195328;        // 65536
  float* bias_out = ws + 4260864;        // 1024
  float* Wgs      = ws + 4261888;        // 1024
  float* sPTv     = ws + 4262912;        // 1024
  float* wgb      = ws + 4263936;        // 256
  float* vpt      = ws + 4264192;        // 256
  float* vb_g     = ws + 4264448;        // 256
  float* t2_g     = ws + 4264704;        // 1024
  float* dvec     = ws + 4265728;        // 8 (pad to 256)
  // bf16 region
  __bf16* at    = (__bf16*)(ws + 4265984);   // 8 MB
  __bf16* Wghi  = (__bf16*)(ws + 6363136);   // 128 KB each below
  __bf16* Wglo  = (__bf16*)(ws + 6395904);
  __bf16* PTthi = (__bf16*)(ws + 6428672);
  __bf16* PTtlo = (__bf16*)(ws + 6461440);
  __bf16* W2hi  = (__bf16*)(ws + 6494208);   // 512 KB each below
  __bf16* W2lo  = (__bf16*)(ws + 6625280);
  __bf16* Whi   = (__bf16*)(ws + 6756352);
  __bf16* Wlo   = (__bf16*)(ws + 6887424);
  __bf16* bhi   = (__bf16*)(ws + 7018496);   // 8 MB
  __bf16* blo   = (__bf16*)(ws + 9115648);   // 8 MB, end ~44.9 MB

  castb_kernel<<<dim3(1024), dim3(256), 0, stream>>>(bI, bhi, blo, srow);
  gram_plus_kernel<<<dim3(1382), dim3(256), 0, stream>>>(bhi, blo, Gpart, a,
                                                         W_w, g_w, phi_w, theta_w,
                                                         phi_b, theta_b, g_b,
                                                         Wg, Wghi, Wglo, PTthi, PTtlo,
                                                         at, vb_g, vpt, wgb, dvec);
  redw2_kernel<<<dim3(128), dim3(256), 0, stream>>>(Gpart, vb_g, t2_g, srow, Wg,
                                                    Wghi, Wglo, PTthi, PTtlo,
                                                    W2hi, W2lo, Wgs, sPTv, dvec);
  wout_mfma_kernel<<<dim3(80), dim3(256), 0, stream>>>(W2hi, W2lo, PTthi, PTtlo,
                                                       Wgs, sPTv, wgb, vpt, Wg, t2_g,
                                                       dvec, bn_gamma, bn_beta, bn_mean,
                                                       bn_var, Whi, Wlo, bias_out);
  out_mfma_kernel<<<dim3(32, 4, 4), dim3(256), 0, stream>>>(Whi, Wlo, at, bias_out, out);
}